// Round 5
// baseline (343.869 us; speedup 1.0000x reference)
//
#include <hip/hip_runtime.h>
#include <hip/hip_bf16.h>
#include <cstddef>

// ---------------------------------------------------------------------------
// MTCNN P-Net forward, NCHW in/out.
//   x[16,3,720,720] -> norm -> conv1(3->10,3x3)+PReLU -> maxpool2 (fp32 math)
//     -> pooled NHWC bf16 (padded 10->16 ch)
//     -> conv2(16->16,3x3) via MFMA 16x16x32 bf16 -> NHWC bf16
//     -> conv3(16->32,3x3)+PReLU via MFMA 32x32x16 bf16, fused heads
//   out = concat(reg[16,4,355,355], prob[16,2,355,355]) flat fp32
// ---------------------------------------------------------------------------

#define H1 718
#define PH 359   // pooled spatial
#define H2 357   // conv2 out spatial
#define H3 355   // conv3 out spatial

// workspace layout (float offsets)
#define W1R_OFF 0              // 270 fp32, pre-scaled by 1/128
#define B1R_OFF 288            // 10 fp32 (norm folded in)
#define AW2_OFF 320            // 2560 bf16 = 1280 fl: conv2 A-frags [step][lane][8]
#define BW3_OFF 1600           // 4608 bf16 = 2304 fl: conv3 B-frags [tap][lane][8]
#define P16_OFF 4096           // pooled NHWC bf16 [16,359,359,16] = 16496768 fl
#define C2H_OFF 16500864       // conv2 out NHWC bf16 [16,357,357,16] = 16313472 fl

typedef short bf16x8 __attribute__((ext_vector_type(8)));
typedef float f32x4  __attribute__((ext_vector_type(4)));
typedef float f32x16 __attribute__((ext_vector_type(16)));
typedef unsigned short ushort4v __attribute__((ext_vector_type(4)));

// ---------------------------------------------------------------------------
// Weight repack.
//  - conv1: fold (x-127.5)/128 into weights/bias (fp32).
//  - conv2: -> MFMA 16x16x32 A-frag order (A = weights, M=c_out), bf16:
//      k in [0,32) of step s: tap = 2s + (k>=16), ci = k&15 (real if ci<10,tap<9)
//      afrag[s][lane][j]: m=lane&15=c_out, k=(lane>>4)*8+j
//  - conv3: -> MFMA 32x32x16 B-frag order, bf16 (as R3, verified).
// ---------------------------------------------------------------------------
__global__ void repack_kernel(const float* __restrict__ w1, const float* __restrict__ b1,
                              const float* __restrict__ w2, const float* __restrict__ w3,
                              float* __restrict__ ws) {
    int t = threadIdx.x;
    const float S = 0.0078125f;
    for (int i = t; i < 270; i += blockDim.x) ws[W1R_OFF + i] = w1[i] * S;
    if (t < 10) {
        float s = 0.f;
        for (int i = 0; i < 27; i++) s += w1[t * 27 + i];
        ws[B1R_OFF + t] = b1[t] - 127.5f * S * s;
    }
    unsigned short* aw2 = (unsigned short*)(ws + AW2_OFF);
    for (int e = t; e < 2560; e += blockDim.x) {
        int s = e >> 9;              // K-step 0..4
        int rem = e & 511;
        int l = rem >> 3, j = rem & 7;
        int q = l >> 4, co = l & 15;
        int tap = 2 * s + (q >> 1);
        int ci  = ((q & 1) << 3) + j;
        float v = (tap < 9 && ci < 10) ? w2[co * 90 + ci * 9 + tap] : 0.f;
        __hip_bfloat16 h = __float2bfloat16(v);
        aw2[e] = *(unsigned short*)&h;
    }
    unsigned short* bw3 = (unsigned short*)(ws + BW3_OFF);
    for (int e = t; e < 4608; e += blockDim.x) {
        int tap = e >> 9;
        int rem = e & 511;
        int l = rem >> 3, j = rem & 7;
        int kh = tap / 3, kw = tap % 3;
        int co = l & 31, ci = ((l >> 5) << 3) + j;
        float v = w3[co * 144 + ci * 9 + kh * 3 + kw];
        __hip_bfloat16 h = __float2bfloat16(v);
        bw3[e] = *(unsigned short*)&h;
    }
}

// ---------------------------------------------------------------------------
// Stage 1: norm+conv1+PReLU+maxpool fused, fp32 math.
// v5: LDS-staged input tile, R0-proven per-thread register shape.
// R1-R3 post-mortem: any body with >~128 live VGPRs spills to scratch
// regardless of __launch_bounds__ (VGPR stuck at 48, +62 MB scratch traffic,
// 102 us). So: keep 1 pooled px / thread (acc[10][4] + win[4][4] ~ 56 live,
// compiles at ~60-90 VGPR), and attack the 40% VALU-idle instead:
//   - block 256 = 64x4 pooled tile; stage 3ci x 10 rows x 130 cols fp32
//     (15.84 KB LDS) once with coalesced float4 loads; windows then come
//     from LDS (ds_read_b64, 8 B lane stride = free 2-way bank aliasing)
//     instead of 24 dependent global loads per thread
//   - halo reuse explicit; global fetch stays read-once
//   - bias folded into acc init; pooled = max(prelu(max4), prelu(min4))
//     (exact: prelu piecewise monotone; both tricks verified passing in R1)
// grid: (6, 90, 16), block 256.
// ---------------------------------------------------------------------------
__global__ __launch_bounds__(256)
void conv1_pool_kernel(const float* __restrict__ x,
                       const float* __restrict__ ws,
                       const float* __restrict__ a1,
                       __hip_bfloat16* __restrict__ p16) {
    __shared__ float xs[3][10][132];   // 15,840 B; 130 cols used, 132 for align

    int tid = threadIdx.x;
    int px0 = blockIdx.x * 64;
    int py0 = blockIdx.y * 4;
    int n   = blockIdx.z;
    int ix0 = 2 * px0;
    int iy0 = 2 * py0;

    // ---- stage: 30 rows (3ci x 10), 33 float4 per row = 990 float4 ----
    for (int i = tid; i < 990; i += 256) {
        int r  = i / 33;              // 0..29
        int c4 = i - r * 33;          // 0..32
        int ci = r / 10, rr = r - (r / 10) * 10;
        int gy = iy0 + rr; if (gy > 719) gy = 719;
        int gx = ix0 + 4 * c4;
        const float* src = x + (((size_t)(n * 3 + ci) * 720 + gy) * 720);
        float4 v;
        if (gx + 3 <= 719) {
            v = *(const float4*)(src + gx);
        } else {
            // gx is a multiple of 4 beyond 716 -> all 4 elements clamp to 719;
            // these values only feed out-of-range pooled columns (guarded).
            float q = src[719];
            v.x = q; v.y = q; v.z = q; v.w = q;
        }
        *(float4*)&xs[ci][rr][4 * c4] = v;
    }
    __syncthreads();

    int tx = tid & 63;
    int ty = tid >> 6;
    int px = px0 + tx;
    int py = py0 + ty;
    if (px >= PH || py >= PH) return;   // no barriers after this point

    int lx = 2 * tx;    // local col base (even -> 8 B aligned float2 reads)
    int ly = 2 * ty;    // local row base

    // bias folded into accumulator init
    float acc[10][4];
    #pragma unroll
    for (int c = 0; c < 10; c++) {
        float b = ws[B1R_OFF + c];
        #pragma unroll
        for (int p = 0; p < 4; p++) acc[c][p] = b;
    }

    #pragma unroll
    for (int ci = 0; ci < 3; ci++) {
        float win[4][4];
        #pragma unroll
        for (int r = 0; r < 4; r++) {
            const float2* rp = (const float2*)&xs[ci][ly + r][lx];
            float2 v0 = rp[0];
            float2 v1 = rp[1];
            win[r][0] = v0.x; win[r][1] = v0.y; win[r][2] = v1.x; win[r][3] = v1.y;
        }
        #pragma unroll
        for (int c = 0; c < 10; c++) {
            const float* wk = ws + W1R_OFF + c * 27 + ci * 9;
            #pragma unroll
            for (int kh = 0; kh < 3; kh++)
                #pragma unroll
                for (int kw = 0; kw < 3; kw++) {
                    float wv = wk[kh * 3 + kw];
                    acc[c][0] = fmaf(win[kh    ][kw    ], wv, acc[c][0]);
                    acc[c][1] = fmaf(win[kh    ][kw + 1], wv, acc[c][1]);
                    acc[c][2] = fmaf(win[kh + 1][kw    ], wv, acc[c][2]);
                    acc[c][3] = fmaf(win[kh + 1][kw + 1], wv, acc[c][3]);
                }
        }
    }

    // epilogue: pooled = max(prelu(max4), prelu(min4)); bf16 pack, pad to 16ch
    __hip_bfloat16 o[16];
    #pragma unroll
    for (int c = 0; c < 10; c++) {
        float al = a1[c];
        float mx = fmaxf(fmaxf(acc[c][0], acc[c][1]), fmaxf(acc[c][2], acc[c][3]));
        float mn = fminf(fminf(acc[c][0], acc[c][1]), fminf(acc[c][2], acc[c][3]));
        float pa = mx >= 0.f ? mx : al * mx;
        float pb = mn >= 0.f ? mn : al * mn;
        o[c] = __float2bfloat16(fmaxf(pa, pb));
    }
    #pragma unroll
    for (int c = 10; c < 16; c++) o[c] = __float2bfloat16(0.f);

    float4* dst = (float4*)(p16 + (((size_t)n * PH + py) * PH + px) * 16);
    dst[0] = ((float4*)o)[0];
    dst[1] = ((float4*)o)[1];
}

// ---------------------------------------------------------------------------
// Stage 2: conv2 3x3 (16pad->16) + bias + PReLU, MFMA 16x16x32 bf16.
// A = weights (M=16 c_out, register-resident), B = pixels (N=16 px) -> D has
// col=px, row=c_out, so the NHWC store is 512 B fully-coalesced per tile
// (lane writes px=(lane&15)'s ch-quad (lane>>4)*4 as one 8 B chunk).
// K=32 = 2 taps x 16ch(10 real); 9 taps -> 5 K-steps, last half zero-padded.
// Wave = 64 px of one output row (4 tiles), 20 MFMA, 18 x 16 B B-loads/lane.
// grid: (ceil(357/64)=6, ceil(357/4)=90, 16), block 256. No barriers.
// ---------------------------------------------------------------------------
__global__ __launch_bounds__(256)
void conv2_mfma_kernel(const __hip_bfloat16* __restrict__ p16,
                       const float* __restrict__ ws,
                       const float* __restrict__ b2,
                       const float* __restrict__ a2,
                       __hip_bfloat16* __restrict__ c2h) {
    int wv = threadIdx.x >> 6;
    int l  = threadIdx.x & 63;
    int oh  = blockIdx.y * 4 + wv;
    int ow0 = blockIdx.x * 64;
    int n   = blockIdx.z;
    if (oh >= H2) return;

    int pxl = l & 15;          // B col: px within tile
    int q   = l >> 4;
    int taph = q >> 1;         // which tap within K-step
    int choff = (q & 1) << 3;  // channel sub-chunk

    const bf16x8* aw = (const bf16x8*)(ws + AW2_OFF);
    bf16x8 afr[5];
    #pragma unroll
    for (int s = 0; s < 5; s++) afr[s] = aw[s * 64 + l];

    bf16x8 zf;
    #pragma unroll
    for (int j = 0; j < 8; j++) zf[j] = 0;

    f32x4 acc[4];
    #pragma unroll
    for (int t = 0; t < 4; t++)
        #pragma unroll
        for (int i = 0; i < 4; i++) acc[t][i] = 0.f;

    #pragma unroll
    for (int s = 0; s < 5; s++) {
        int tap = 2 * s + taph;
        bool real = (tap < 9);
        int kh = tap / 3, kw = tap - kh * 3;
        int ih = oh + kh; if (ih > PH - 1) ih = PH - 1;   // only pad-tap can exceed
        #pragma unroll
        for (int t = 0; t < 4; t++) {
            int iw = ow0 + t * 16 + pxl + kw; if (iw > PH - 1) iw = PH - 1;
            const bf16x8* bp = (const bf16x8*)(p16 + (((size_t)n * PH + ih) * PH + iw) * 16 + choff);
            bf16x8 b = real ? *bp : zf;
            acc[t] = __builtin_amdgcn_mfma_f32_16x16x32_bf16(afr[s], b, acc[t], 0, 0, 0);
        }
    }

    // epilogue: bias+PReLU; lane's elements are (c_out = q*4+r, px = pxl)
    float bb[4], aa[4];
    #pragma unroll
    for (int r = 0; r < 4; r++) { bb[r] = b2[q * 4 + r]; aa[r] = a2[q * 4 + r]; }

    #pragma unroll
    for (int t = 0; t < 4; t++) {
        int px = ow0 + t * 16 + pxl;
        if (px < H2) {
            ushort4v pk;
            #pragma unroll
            for (int r = 0; r < 4; r++) {
                float v = acc[t][r] + bb[r];
                v = v >= 0.f ? v : aa[r] * v;
                __hip_bfloat16 h = __float2bfloat16(v);
                pk[r] = *(unsigned short*)&h;
            }
            *(ushort4v*)(c2h + (((size_t)n * H2 + oh) * H2 + px) * 16 + q * 4) = pk;
        }
    }
}

// ---------------------------------------------------------------------------
// Stage 3: conv3 3x3 (16->32) + PReLU + heads, MFMA 32x32x16 bf16 (R3,
// verified). A = pixels, B = weights; heads via stride-33 LDS; softmax.
// grid: (12, 45, 16), block 256
// ---------------------------------------------------------------------------
__global__ __launch_bounds__(256, 1)
void conv3_heads_kernel(const __hip_bfloat16* __restrict__ c2h,
                        const float* __restrict__ ws,
                        const float* __restrict__ b3,
                        const float* __restrict__ a3,
                        const float* __restrict__ w41,
                        const float* __restrict__ b41,
                        const float* __restrict__ w42,
                        const float* __restrict__ b42,
                        float* __restrict__ out) {
    int wv = threadIdx.x >> 6;
    int l  = threadIdx.x & 63;
    int ow0 = blockIdx.x * 32;
    int oh0 = blockIdx.y * 8 + wv * 2;
    int n   = blockIdx.z;

    int m    = l & 31;
    int half = l >> 5;
    int choff = half << 3;

    const bf16x8* bw = (const bf16x8*)(ws + BW3_OFF);
    bf16x8 bfr[9];
    #pragma unroll
    for (int t = 0; t < 9; t++) bfr[t] = bw[t * 64 + l];

    f32x16 acc0, acc1;
    #pragma unroll
    for (int i = 0; i < 16; i++) { acc0[i] = 0.f; acc1[i] = 0.f; }

    #pragma unroll
    for (int kh = 0; kh < 3; kh++) {
        int ih0 = oh0 + kh;     if (ih0 > H2 - 1) ih0 = H2 - 1;
        int ih1 = oh0 + 1 + kh; if (ih1 > H2 - 1) ih1 = H2 - 1;
        #pragma unroll
        for (int kw = 0; kw < 3; kw++) {
            int iw = ow0 + m + kw; if (iw > H2 - 1) iw = H2 - 1;
            const bf16x8* a0p = (const bf16x8*)(c2h + ((((size_t)n * H2 + ih0) * H2 + iw) << 4) + choff);
            const bf16x8* a1p = (const bf16x8*)(c2h + ((((size_t)n * H2 + ih1) * H2 + iw) << 4) + choff);
            bf16x8 a0 = *a0p;
            bf16x8 a1 = *a1p;
            int tap = kh * 3 + kw;
            acc0 = __builtin_amdgcn_mfma_f32_32x32x16_bf16(a0, bfr[tap], acc0, 0, 0, 0);
            acc1 = __builtin_amdgcn_mfma_f32_32x32x16_bf16(a1, bfr[tap], acc1, 0, 0, 0);
        }
    }

    __shared__ float hbuf[4][64 * 33];
    float* hb = hbuf[wv];
    float bb = b3[m], aa = a3[m];
    #pragma unroll
    for (int t = 0; t < 2; t++) {
        #pragma unroll
        for (int r = 0; r < 16; r++) {
            int mprime = (r & 3) + ((r >> 2) << 3) + (half << 2);
            float v = (t ? acc1[r] : acc0[r]) + bb;
            v = v >= 0.f ? v : aa * v;
            hb[(t * 32 + mprime) * 33 + m] = v;
        }
    }
    __syncthreads();

    int poh = oh0 + (l >> 5);
    int pow_ = ow0 + (l & 31);
    float h[32];
    #pragma unroll
    for (int c = 0; c < 32; c++) h[c] = hb[l * 33 + c];

    float l0 = b41[0], l1 = b41[1];
    float r0 = b42[0], r1 = b42[1], r2 = b42[2], r3 = b42[3];
    #pragma unroll
    for (int c = 0; c < 32; c++) {
        float hv = h[c];
        l0 = fmaf(hv, w41[c],      l0);
        l1 = fmaf(hv, w41[32 + c], l1);
        r0 = fmaf(hv, w42[c],      r0);
        r1 = fmaf(hv, w42[32 + c], r1);
        r2 = fmaf(hv, w42[64 + c], r2);
        r3 = fmaf(hv, w42[96 + c], r3);
    }
    float mx  = fmaxf(l0, l1);
    float e0 = __expf(l0 - mx), e1 = __expf(l1 - mx);
    float inv = 1.0f / (e0 + e1);

    if (poh < H3 && pow_ < H3) {
        const size_t sp = (size_t)H3 * H3;
        size_t pos = (size_t)poh * H3 + pow_;
        float* reg  = out;
        float* prob = out + (size_t)16 * 4 * sp;
        reg[((size_t)(n * 4 + 0)) * sp + pos] = r0;
        reg[((size_t)(n * 4 + 1)) * sp + pos] = r1;
        reg[((size_t)(n * 4 + 2)) * sp + pos] = r2;
        reg[((size_t)(n * 4 + 3)) * sp + pos] = r3;
        prob[((size_t)(n * 2 + 0)) * sp + pos] = e0 * inv;
        prob[((size_t)(n * 2 + 1)) * sp + pos] = e1 * inv;
    }
}

extern "C" void kernel_launch(void* const* d_in, const int* in_sizes, int n_in,
                              void* d_out, int out_size, void* d_ws, size_t ws_size,
                              hipStream_t stream) {
    const float* x   = (const float*)d_in[0];
    const float* w1  = (const float*)d_in[1];
    const float* b1  = (const float*)d_in[2];
    const float* a1  = (const float*)d_in[3];
    const float* w2  = (const float*)d_in[4];
    const float* b2  = (const float*)d_in[5];
    const float* a2  = (const float*)d_in[6];
    const float* w3  = (const float*)d_in[7];
    const float* b3  = (const float*)d_in[8];
    const float* a3  = (const float*)d_in[9];
    const float* w41 = (const float*)d_in[10];
    const float* b41 = (const float*)d_in[11];
    const float* w42 = (const float*)d_in[12];
    const float* b42 = (const float*)d_in[13];
    float* out = (float*)d_out;
    float* ws  = (float*)d_ws;

    __hip_bfloat16* p16 = (__hip_bfloat16*)(ws + P16_OFF);
    __hip_bfloat16* c2h = (__hip_bfloat16*)(ws + C2H_OFF);

    repack_kernel<<<1, 256, 0, stream>>>(w1, b1, w2, w3, ws);

    {
        // 64x4 pooled tile per 256-thread block, LDS-staged input
        dim3 grid((PH + 63) / 64, (PH + 3) / 4, 16);
        conv1_pool_kernel<<<grid, 256, 0, stream>>>(x, ws, a1, p16);
    }
    {
        dim3 grid((H2 + 63) / 64, (H2 + 3) / 4, 16);
        conv2_mfma_kernel<<<grid, 256, 0, stream>>>(p16, ws, b2, a2, c2h);
    }
    {
        dim3 grid((H3 + 31) / 32, (H3 + 7) / 8, 16);
        conv3_heads_kernel<<<grid, 256, 0, stream>>>(c2h, ws, b3, a3,
                                                     w41, b41, w42, b42, out);
    }
}

// Round 7
// 309.546 us; speedup vs baseline: 1.1109x; 1.1109x over previous
//
#include <hip/hip_runtime.h>
#include <hip/hip_bf16.h>
#include <cstddef>

// ---------------------------------------------------------------------------
// MTCNN P-Net forward, NCHW in/out.
//   x[16,3,720,720] -> norm -> conv1(3->10,3x3)+PReLU -> maxpool2 (fp32 math)
//     -> pooled NHWC bf16 (padded 10->16 ch)
//     -> conv2(16->16,3x3) via MFMA 16x16x32 bf16 -> NHWC bf16
//     -> conv3(16->32,3x3)+PReLU via MFMA 32x32x16 bf16, fused heads
//   out = concat(reg[16,4,355,355], prob[16,2,355,355]) flat fp32
// ---------------------------------------------------------------------------

#define H1 718
#define PH 359   // pooled spatial
#define H2 357   // conv2 out spatial
#define H3 355   // conv3 out spatial

// workspace layout (float offsets)
#define W1R_OFF 0              // 270 fp32, pre-scaled by 1/128
#define B1R_OFF 288            // 10 fp32 (norm folded in)
#define AW2_OFF 320            // 2560 bf16 = 1280 fl: conv2 A-frags [step][lane][8]
#define BW3_OFF 1600           // 4608 bf16 = 2304 fl: conv3 B-frags [tap][lane][8]
#define P16_OFF 4096           // pooled NHWC bf16 [16,359,359,16] = 16496768 fl
#define C2H_OFF 16500864       // conv2 out NHWC bf16 [16,357,357,16] = 16313472 fl

typedef short bf16x8 __attribute__((ext_vector_type(8)));
typedef float f32x4  __attribute__((ext_vector_type(4)));
typedef float f32x16 __attribute__((ext_vector_type(16)));
typedef unsigned short ushort4v __attribute__((ext_vector_type(4)));

// ---------------------------------------------------------------------------
// Weight repack — R6: parallelized across 29 blocks (was 1 block = 1 CU,
// ~7.4k dependent global-load chains serialized on 256 threads).
//   block 0      : conv1 fp32 scale + bias fold
//   blocks 1..10 : conv2 A-frags (2560 = 10 x 256)
//   blocks 11..28: conv3 B-frags (4608 = 18 x 256)
// Frag orders byte-identical to the verified single-block version.
// ---------------------------------------------------------------------------
__global__ void repack_kernel(const float* __restrict__ w1, const float* __restrict__ b1,
                              const float* __restrict__ w2, const float* __restrict__ w3,
                              float* __restrict__ ws) {
    int t = threadIdx.x;
    int bid = blockIdx.x;
    if (bid == 0) {
        const float S = 0.0078125f;
        for (int i = t; i < 270; i += 256) ws[W1R_OFF + i] = w1[i] * S;
        if (t < 10) {
            float s = 0.f;
            for (int i = 0; i < 27; i++) s += w1[t * 27 + i];
            ws[B1R_OFF + t] = b1[t] - 127.5f * S * s;
        }
    } else if (bid <= 10) {
        int e = (bid - 1) * 256 + t;  // 0..2559
        unsigned short* aw2 = (unsigned short*)(ws + AW2_OFF);
        int s = e >> 9;              // K-step 0..4
        int rem = e & 511;
        int l = rem >> 3, j = rem & 7;
        int q = l >> 4, co = l & 15;
        int tap = 2 * s + (q >> 1);
        int ci  = ((q & 1) << 3) + j;
        float v = (tap < 9 && ci < 10) ? w2[co * 90 + ci * 9 + tap] : 0.f;
        __hip_bfloat16 h = __float2bfloat16(v);
        aw2[e] = *(unsigned short*)&h;
    } else {
        int e = (bid - 11) * 256 + t; // 0..4607
        unsigned short* bw3 = (unsigned short*)(ws + BW3_OFF);
        int tap = e >> 9;
        int rem = e & 511;
        int l = rem >> 3, j = rem & 7;
        int kh = tap / 3, kw = tap % 3;
        int co = l & 31, ci = ((l >> 5) << 3) + j;
        float v = w3[co * 144 + ci * 9 + kh * 3 + kw];
        __hip_bfloat16 h = __float2bfloat16(v);
        bw3[e] = *(unsigned short*)&h;
    }
}

// ---------------------------------------------------------------------------
// Stage 1: norm+conv1+PReLU+maxpool fused, all 10 channels per thread.
// EXACT R0 body (75.8 us, VGPR 60, no spill — every variant tried in R1-R5
// regressed: 2px/thread spills to scratch regardless of launch_bounds;
// LDS staging replaces L1 hits with ds_read issue cost, +31 us VALU time).
// fp32 math; output NHWC bf16 padded to 16 ch (one 32 B store per thread).
// grid: (3, 359, 16), block 128.
// ---------------------------------------------------------------------------
__global__ void conv1_pool_kernel(const float* __restrict__ x,
                                  const float* __restrict__ ws,
                                  const float* __restrict__ a1,
                                  __hip_bfloat16* __restrict__ p16) {
    int pw = blockIdx.x * blockDim.x + threadIdx.x;
    int ph = blockIdx.y;
    int n  = blockIdx.z;
    if (pw >= PH) return;
    int iy = 2 * ph, ix = 2 * pw;

    float acc[10][4];
    #pragma unroll
    for (int c = 0; c < 10; c++)
        #pragma unroll
        for (int p = 0; p < 4; p++) acc[c][p] = 0.f;

    #pragma unroll
    for (int ci = 0; ci < 3; ci++) {
        const float* xp = x + (((size_t)(n * 3 + ci) * 720 + iy) * 720 + ix);
        float win[4][4];
        #pragma unroll
        for (int r = 0; r < 4; r++) {
            float2 v0 = *(const float2*)(xp + r * 720);
            float2 v1 = *(const float2*)(xp + r * 720 + 2);
            win[r][0] = v0.x; win[r][1] = v0.y; win[r][2] = v1.x; win[r][3] = v1.y;
        }
        #pragma unroll
        for (int c = 0; c < 10; c++) {
            const float* wk = ws + W1R_OFF + c * 27 + ci * 9;
            #pragma unroll
            for (int kh = 0; kh < 3; kh++)
                #pragma unroll
                for (int kw = 0; kw < 3; kw++) {
                    float wv = wk[kh * 3 + kw];
                    acc[c][0] = fmaf(win[kh    ][kw    ], wv, acc[c][0]);
                    acc[c][1] = fmaf(win[kh    ][kw + 1], wv, acc[c][1]);
                    acc[c][2] = fmaf(win[kh + 1][kw    ], wv, acc[c][2]);
                    acc[c][3] = fmaf(win[kh + 1][kw + 1], wv, acc[c][3]);
                }
        }
    }

    __hip_bfloat16 o[16];
    #pragma unroll
    for (int c = 0; c < 10; c++) {
        float b = ws[B1R_OFF + c], al = a1[c];
        float s0 = acc[c][0] + b, s1 = acc[c][1] + b;
        float s2 = acc[c][2] + b, s3 = acc[c][3] + b;
        s0 = s0 >= 0.f ? s0 : al * s0;
        s1 = s1 >= 0.f ? s1 : al * s1;
        s2 = s2 >= 0.f ? s2 : al * s2;
        s3 = s3 >= 0.f ? s3 : al * s3;
        o[c] = __float2bfloat16(fmaxf(fmaxf(s0, s1), fmaxf(s2, s3)));
    }
    #pragma unroll
    for (int c = 10; c < 16; c++) o[c] = __float2bfloat16(0.f);

    float4* dst = (float4*)(p16 + (((size_t)n * PH + ph) * PH + pw) * 16);
    dst[0] = ((float4*)o)[0];
    dst[1] = ((float4*)o)[1];
}

// ---------------------------------------------------------------------------
// Stage 2: conv2 3x3 (16pad->16) + bias + PReLU, MFMA 16x16x32 bf16.
// A = weights (M=16 c_out, register-resident), B = pixels (N=16 px) -> D has
// col=px, row=c_out, so the NHWC store is 512 B fully-coalesced per tile
// (lane writes px=(lane&15)'s ch-quad (lane>>4)*4 as one 8 B chunk).
// K=32 = 2 taps x 16ch(10 real); 9 taps -> 5 K-steps, last half zero-padded.
// Wave = 64 px of one output row (4 tiles), 20 MFMA, 18 x 16 B B-loads/lane.
// grid: (ceil(357/64)=6, ceil(357/4)=90, 16), block 256. No barriers.
// ---------------------------------------------------------------------------
__global__ __launch_bounds__(256)
void conv2_mfma_kernel(const __hip_bfloat16* __restrict__ p16,
                       const float* __restrict__ ws,
                       const float* __restrict__ b2,
                       const float* __restrict__ a2,
                       __hip_bfloat16* __restrict__ c2h) {
    int wv = threadIdx.x >> 6;
    int l  = threadIdx.x & 63;
    int oh  = blockIdx.y * 4 + wv;
    int ow0 = blockIdx.x * 64;
    int n   = blockIdx.z;
    if (oh >= H2) return;

    int pxl = l & 15;          // B col: px within tile
    int q   = l >> 4;
    int taph = q >> 1;         // which tap within K-step
    int choff = (q & 1) << 3;  // channel sub-chunk

    const bf16x8* aw = (const bf16x8*)(ws + AW2_OFF);
    bf16x8 afr[5];
    #pragma unroll
    for (int s = 0; s < 5; s++) afr[s] = aw[s * 64 + l];

    bf16x8 zf;
    #pragma unroll
    for (int j = 0; j < 8; j++) zf[j] = 0;

    f32x4 acc[4];
    #pragma unroll
    for (int t = 0; t < 4; t++)
        #pragma unroll
        for (int i = 0; i < 4; i++) acc[t][i] = 0.f;

    #pragma unroll
    for (int s = 0; s < 5; s++) {
        int tap = 2 * s + taph;
        bool real = (tap < 9);
        int kh = tap / 3, kw = tap - kh * 3;
        int ih = oh + kh; if (ih > PH - 1) ih = PH - 1;   // only pad-tap can exceed
        #pragma unroll
        for (int t = 0; t < 4; t++) {
            int iw = ow0 + t * 16 + pxl + kw; if (iw > PH - 1) iw = PH - 1;
            const bf16x8* bp = (const bf16x8*)(p16 + (((size_t)n * PH + ih) * PH + iw) * 16 + choff);
            bf16x8 b = real ? *bp : zf;
            acc[t] = __builtin_amdgcn_mfma_f32_16x16x32_bf16(afr[s], b, acc[t], 0, 0, 0);
        }
    }

    // epilogue: bias+PReLU; lane's elements are (c_out = q*4+r, px = pxl)
    float bb[4], aa[4];
    #pragma unroll
    for (int r = 0; r < 4; r++) { bb[r] = b2[q * 4 + r]; aa[r] = a2[q * 4 + r]; }

    #pragma unroll
    for (int t = 0; t < 4; t++) {
        int px = ow0 + t * 16 + pxl;
        if (px < H2) {
            ushort4v pk;
            #pragma unroll
            for (int r = 0; r < 4; r++) {
                float v = acc[t][r] + bb[r];
                v = v >= 0.f ? v : aa[r] * v;
                __hip_bfloat16 h = __float2bfloat16(v);
                pk[r] = *(unsigned short*)&h;
            }
            *(ushort4v*)(c2h + (((size_t)n * H2 + oh) * H2 + px) * 16 + q * 4) = pk;
        }
    }
}

// ---------------------------------------------------------------------------
// Stage 3: conv3 3x3 (16->32) + PReLU + heads, MFMA 32x32x16 bf16.
// R6b: row-load dedup — rows oh0+1/oh0+2 were loaded twice (once for each
// accumulator's tap neighborhood); now 4 distinct rows x 3 kw = 12 loads
// (was 18), held in registers ar0..ar3 (renamed: 'a3' collided with the
// PReLU parameter — R6 compile failure). Next-row loads issue between MFMA
// clusters (natural pipelining). Clamps and bfr tap indexing identical to
// the verified version.
// A = pixels, B = weights; heads via stride-33 LDS; softmax.
// grid: (12, 45, 16), block 256
// ---------------------------------------------------------------------------
__global__ __launch_bounds__(256, 1)
void conv3_heads_kernel(const __hip_bfloat16* __restrict__ c2h,
                        const float* __restrict__ ws,
                        const float* __restrict__ b3,
                        const float* __restrict__ a3,
                        const float* __restrict__ w41,
                        const float* __restrict__ b41,
                        const float* __restrict__ w42,
                        const float* __restrict__ b42,
                        float* __restrict__ out) {
    int wv = threadIdx.x >> 6;
    int l  = threadIdx.x & 63;
    int ow0 = blockIdx.x * 32;
    int oh0 = blockIdx.y * 8 + wv * 2;
    int n   = blockIdx.z;

    int m    = l & 31;
    int half = l >> 5;
    int choff = half << 3;

    const bf16x8* bw = (const bf16x8*)(ws + BW3_OFF);
    bf16x8 bfr[9];
    #pragma unroll
    for (int t = 0; t < 9; t++) bfr[t] = bw[t * 64 + l];

    f32x16 acc0, acc1;
    #pragma unroll
    for (int i = 0; i < 16; i++) { acc0[i] = 0.f; acc1[i] = 0.f; }

    // clamped row/col indices (same clamping as verified version)
    int row0 = oh0;     if (row0 > H2 - 1) row0 = H2 - 1;
    int row1 = oh0 + 1; if (row1 > H2 - 1) row1 = H2 - 1;
    int row2 = oh0 + 2; if (row2 > H2 - 1) row2 = H2 - 1;
    int row3 = oh0 + 3; if (row3 > H2 - 1) row3 = H2 - 1;
    int iwc[3];
    #pragma unroll
    for (int kw = 0; kw < 3; kw++) {
        int iw = ow0 + m + kw; if (iw > H2 - 1) iw = H2 - 1;
        iwc[kw] = iw;
    }

#define LD_ROW(dst, r)                                                          \
    {                                                                           \
        const size_t rb = (((size_t)n * H2 + (r)) * H2);                        \
        dst[0] = *(const bf16x8*)(c2h + ((rb + iwc[0]) << 4) + choff);          \
        dst[1] = *(const bf16x8*)(c2h + ((rb + iwc[1]) << 4) + choff);          \
        dst[2] = *(const bf16x8*)(c2h + ((rb + iwc[2]) << 4) + choff);          \
    }

    bf16x8 ar0[3], ar1[3], ar2[3], ar3[3];
    LD_ROW(ar0, row0);
    LD_ROW(ar1, row1);
    // kh = 0: acc0 uses row0, acc1 uses row1, taps 0..2
    acc0 = __builtin_amdgcn_mfma_f32_32x32x16_bf16(ar0[0], bfr[0], acc0, 0, 0, 0);
    acc1 = __builtin_amdgcn_mfma_f32_32x32x16_bf16(ar1[0], bfr[0], acc1, 0, 0, 0);
    acc0 = __builtin_amdgcn_mfma_f32_32x32x16_bf16(ar0[1], bfr[1], acc0, 0, 0, 0);
    acc1 = __builtin_amdgcn_mfma_f32_32x32x16_bf16(ar1[1], bfr[1], acc1, 0, 0, 0);
    acc0 = __builtin_amdgcn_mfma_f32_32x32x16_bf16(ar0[2], bfr[2], acc0, 0, 0, 0);
    acc1 = __builtin_amdgcn_mfma_f32_32x32x16_bf16(ar1[2], bfr[2], acc1, 0, 0, 0);
    LD_ROW(ar2, row2);
    // kh = 1: acc0 uses row1, acc1 uses row2, taps 3..5
    acc0 = __builtin_amdgcn_mfma_f32_32x32x16_bf16(ar1[0], bfr[3], acc0, 0, 0, 0);
    acc1 = __builtin_amdgcn_mfma_f32_32x32x16_bf16(ar2[0], bfr[3], acc1, 0, 0, 0);
    acc0 = __builtin_amdgcn_mfma_f32_32x32x16_bf16(ar1[1], bfr[4], acc0, 0, 0, 0);
    acc1 = __builtin_amdgcn_mfma_f32_32x32x16_bf16(ar2[1], bfr[4], acc1, 0, 0, 0);
    acc0 = __builtin_amdgcn_mfma_f32_32x32x16_bf16(ar1[2], bfr[5], acc0, 0, 0, 0);
    acc1 = __builtin_amdgcn_mfma_f32_32x32x16_bf16(ar2[2], bfr[5], acc1, 0, 0, 0);
    LD_ROW(ar3, row3);
    // kh = 2: acc0 uses row2, acc1 uses row3, taps 6..8
    acc0 = __builtin_amdgcn_mfma_f32_32x32x16_bf16(ar2[0], bfr[6], acc0, 0, 0, 0);
    acc1 = __builtin_amdgcn_mfma_f32_32x32x16_bf16(ar3[0], bfr[6], acc1, 0, 0, 0);
    acc0 = __builtin_amdgcn_mfma_f32_32x32x16_bf16(ar2[1], bfr[7], acc0, 0, 0, 0);
    acc1 = __builtin_amdgcn_mfma_f32_32x32x16_bf16(ar3[1], bfr[7], acc1, 0, 0, 0);
    acc0 = __builtin_amdgcn_mfma_f32_32x32x16_bf16(ar2[2], bfr[8], acc0, 0, 0, 0);
    acc1 = __builtin_amdgcn_mfma_f32_32x32x16_bf16(ar3[2], bfr[8], acc1, 0, 0, 0);
#undef LD_ROW

    __shared__ float hbuf[4][64 * 33];
    float* hb = hbuf[wv];
    float bb = b3[m], aa = a3[m];
    #pragma unroll
    for (int t = 0; t < 2; t++) {
        #pragma unroll
        for (int r = 0; r < 16; r++) {
            int mprime = (r & 3) + ((r >> 2) << 3) + (half << 2);
            float v = (t ? acc1[r] : acc0[r]) + bb;
            v = v >= 0.f ? v : aa * v;
            hb[(t * 32 + mprime) * 33 + m] = v;
        }
    }
    __syncthreads();

    int poh = oh0 + (l >> 5);
    int pow_ = ow0 + (l & 31);
    float h[32];
    #pragma unroll
    for (int c = 0; c < 32; c++) h[c] = hb[l * 33 + c];

    float l0 = b41[0], l1 = b41[1];
    float r0 = b42[0], r1 = b42[1], r2 = b42[2], r3 = b42[3];
    #pragma unroll
    for (int c = 0; c < 32; c++) {
        float hv = h[c];
        l0 = fmaf(hv, w41[c],      l0);
        l1 = fmaf(hv, w41[32 + c], l1);
        r0 = fmaf(hv, w42[c],      r0);
        r1 = fmaf(hv, w42[32 + c], r1);
        r2 = fmaf(hv, w42[64 + c], r2);
        r3 = fmaf(hv, w42[96 + c], r3);
    }
    float mx  = fmaxf(l0, l1);
    float e0 = __expf(l0 - mx), e1 = __expf(l1 - mx);
    float inv = 1.0f / (e0 + e1);

    if (poh < H3 && pow_ < H3) {
        const size_t sp = (size_t)H3 * H3;
        size_t pos = (size_t)poh * H3 + pow_;
        float* reg  = out;
        float* prob = out + (size_t)16 * 4 * sp;
        reg[((size_t)(n * 4 + 0)) * sp + pos] = r0;
        reg[((size_t)(n * 4 + 1)) * sp + pos] = r1;
        reg[((size_t)(n * 4 + 2)) * sp + pos] = r2;
        reg[((size_t)(n * 4 + 3)) * sp + pos] = r3;
        prob[((size_t)(n * 2 + 0)) * sp + pos] = e0 * inv;
        prob[((size_t)(n * 2 + 1)) * sp + pos] = e1 * inv;
    }
}

extern "C" void kernel_launch(void* const* d_in, const int* in_sizes, int n_in,
                              void* d_out, int out_size, void* d_ws, size_t ws_size,
                              hipStream_t stream) {
    const float* x   = (const float*)d_in[0];
    const float* w1  = (const float*)d_in[1];
    const float* b1  = (const float*)d_in[2];
    const float* a1  = (const float*)d_in[3];
    const float* w2  = (const float*)d_in[4];
    const float* b2  = (const float*)d_in[5];
    const float* a2  = (const float*)d_in[6];
    const float* w3  = (const float*)d_in[7];
    const float* b3  = (const float*)d_in[8];
    const float* a3  = (const float*)d_in[9];
    const float* w41 = (const float*)d_in[10];
    const float* b41 = (const float*)d_in[11];
    const float* w42 = (const float*)d_in[12];
    const float* b42 = (const float*)d_in[13];
    float* out = (float*)d_out;
    float* ws  = (float*)d_ws;

    __hip_bfloat16* p16 = (__hip_bfloat16*)(ws + P16_OFF);
    __hip_bfloat16* c2h = (__hip_bfloat16*)(ws + C2H_OFF);

    repack_kernel<<<29, 256, 0, stream>>>(w1, b1, w2, w3, ws);

    {
        dim3 grid((PH + 127) / 128, PH, 16);
        conv1_pool_kernel<<<grid, 128, 0, stream>>>(x, ws, a1, p16);
    }
    {
        dim3 grid((H2 + 63) / 64, (H2 + 3) / 4, 16);
        conv2_mfma_kernel<<<grid, 256, 0, stream>>>(p16, ws, b2, a2, c2h);
    }
    {
        dim3 grid((H3 + 31) / 32, (H3 + 7) / 8, 16);
        conv3_heads_kernel<<<grid, 256, 0, stream>>>(c2h, ws, b3, a3,
                                                     w41, b41, w42, b42, out);
    }
}

// Round 8
// 306.327 us; speedup vs baseline: 1.1226x; 1.0105x over previous
//
#include <hip/hip_runtime.h>
#include <hip/hip_bf16.h>
#include <cstddef>

// ---------------------------------------------------------------------------
// MTCNN P-Net forward, NCHW in/out.
//   x[16,3,720,720] -> norm -> conv1(3->10,3x3)+PReLU -> maxpool2 (fp32 math)
//     -> pooled NHWC bf16 (padded 10->16 ch)
//     -> conv2(16->16,3x3) via MFMA 16x16x32 bf16 -> NHWC bf16
//     -> conv3(16->32,3x3)+PReLU via MFMA 32x32x16 bf16, fused heads
//   out = concat(reg[16,4,355,355], prob[16,2,355,355]) flat fp32
// ---------------------------------------------------------------------------

#define H1 718
#define PH 359   // pooled spatial
#define H2 357   // conv2 out spatial
#define H3 355   // conv3 out spatial

// workspace layout (float offsets)
#define W1R_OFF 0              // 270 fp32, pre-scaled by 1/128
#define B1R_OFF 288            // 10 fp32 (norm folded in)
#define AW2_OFF 320            // 2560 bf16 = 1280 fl: conv2 A-frags [step][lane][8]
#define BW3_OFF 1600           // 4608 bf16 = 2304 fl: conv3 B-frags [tap][lane][8]
#define P16_OFF 4096           // pooled NHWC bf16 [16,359,359,16] = 16496768 fl
#define C2H_OFF 16500864       // conv2 out NHWC bf16 [16,357,357,16] = 16313472 fl

typedef short bf16x8 __attribute__((ext_vector_type(8)));
typedef float f32x4  __attribute__((ext_vector_type(4)));
typedef float f32x16 __attribute__((ext_vector_type(16)));
typedef unsigned short ushort4v __attribute__((ext_vector_type(4)));

// ---------------------------------------------------------------------------
// Weight repack — parallelized across 29 blocks (R6; verified).
//   block 0      : conv1 fp32 scale + bias fold
//   blocks 1..10 : conv2 A-frags (2560 = 10 x 256)
//   blocks 11..28: conv3 B-frags (4608 = 18 x 256)
// ---------------------------------------------------------------------------
__global__ void repack_kernel(const float* __restrict__ w1, const float* __restrict__ b1,
                              const float* __restrict__ w2, const float* __restrict__ w3,
                              float* __restrict__ ws) {
    int t = threadIdx.x;
    int bid = blockIdx.x;
    if (bid == 0) {
        const float S = 0.0078125f;
        for (int i = t; i < 270; i += 256) ws[W1R_OFF + i] = w1[i] * S;
        if (t < 10) {
            float s = 0.f;
            for (int i = 0; i < 27; i++) s += w1[t * 27 + i];
            ws[B1R_OFF + t] = b1[t] - 127.5f * S * s;
        }
    } else if (bid <= 10) {
        int e = (bid - 1) * 256 + t;  // 0..2559
        unsigned short* aw2 = (unsigned short*)(ws + AW2_OFF);
        int s = e >> 9;              // K-step 0..4
        int rem = e & 511;
        int l = rem >> 3, j = rem & 7;
        int q = l >> 4, co = l & 15;
        int tap = 2 * s + (q >> 1);
        int ci  = ((q & 1) << 3) + j;
        float v = (tap < 9 && ci < 10) ? w2[co * 90 + ci * 9 + tap] : 0.f;
        __hip_bfloat16 h = __float2bfloat16(v);
        aw2[e] = *(unsigned short*)&h;
    } else {
        int e = (bid - 11) * 256 + t; // 0..4607
        unsigned short* bw3 = (unsigned short*)(ws + BW3_OFF);
        int tap = e >> 9;
        int rem = e & 511;
        int l = rem >> 3, j = rem & 7;
        int kh = tap / 3, kw = tap % 3;
        int co = l & 31, ci = ((l >> 5) << 3) + j;
        float v = w3[co * 144 + ci * 9 + kh * 3 + kw];
        __hip_bfloat16 h = __float2bfloat16(v);
        bw3[e] = *(unsigned short*)&h;
    }
}

// ---------------------------------------------------------------------------
// Stage 1: norm+conv1+PReLU+maxpool fused, all 10 channels per thread.
// EXACT R0 body (75.8 us, VGPR 60, no spill — R1-R5: every variant regressed).
// grid: (3, 359, 16), block 128.
// ---------------------------------------------------------------------------
__global__ void conv1_pool_kernel(const float* __restrict__ x,
                                  const float* __restrict__ ws,
                                  const float* __restrict__ a1,
                                  __hip_bfloat16* __restrict__ p16) {
    int pw = blockIdx.x * blockDim.x + threadIdx.x;
    int ph = blockIdx.y;
    int n  = blockIdx.z;
    if (pw >= PH) return;
    int iy = 2 * ph, ix = 2 * pw;

    float acc[10][4];
    #pragma unroll
    for (int c = 0; c < 10; c++)
        #pragma unroll
        for (int p = 0; p < 4; p++) acc[c][p] = 0.f;

    #pragma unroll
    for (int ci = 0; ci < 3; ci++) {
        const float* xp = x + (((size_t)(n * 3 + ci) * 720 + iy) * 720 + ix);
        float win[4][4];
        #pragma unroll
        for (int r = 0; r < 4; r++) {
            float2 v0 = *(const float2*)(xp + r * 720);
            float2 v1 = *(const float2*)(xp + r * 720 + 2);
            win[r][0] = v0.x; win[r][1] = v0.y; win[r][2] = v1.x; win[r][3] = v1.y;
        }
        #pragma unroll
        for (int c = 0; c < 10; c++) {
            const float* wk = ws + W1R_OFF + c * 27 + ci * 9;
            #pragma unroll
            for (int kh = 0; kh < 3; kh++)
                #pragma unroll
                for (int kw = 0; kw < 3; kw++) {
                    float wv = wk[kh * 3 + kw];
                    acc[c][0] = fmaf(win[kh    ][kw    ], wv, acc[c][0]);
                    acc[c][1] = fmaf(win[kh    ][kw + 1], wv, acc[c][1]);
                    acc[c][2] = fmaf(win[kh + 1][kw    ], wv, acc[c][2]);
                    acc[c][3] = fmaf(win[kh + 1][kw + 1], wv, acc[c][3]);
                }
        }
    }

    __hip_bfloat16 o[16];
    #pragma unroll
    for (int c = 0; c < 10; c++) {
        float b = ws[B1R_OFF + c], al = a1[c];
        float s0 = acc[c][0] + b, s1 = acc[c][1] + b;
        float s2 = acc[c][2] + b, s3 = acc[c][3] + b;
        s0 = s0 >= 0.f ? s0 : al * s0;
        s1 = s1 >= 0.f ? s1 : al * s1;
        s2 = s2 >= 0.f ? s2 : al * s2;
        s3 = s3 >= 0.f ? s3 : al * s3;
        o[c] = __float2bfloat16(fmaxf(fmaxf(s0, s1), fmaxf(s2, s3)));
    }
    #pragma unroll
    for (int c = 10; c < 16; c++) o[c] = __float2bfloat16(0.f);

    float4* dst = (float4*)(p16 + (((size_t)n * PH + ph) * PH + pw) * 16);
    dst[0] = ((float4*)o)[0];
    dst[1] = ((float4*)o)[1];
}

// ---------------------------------------------------------------------------
// Stage 2: conv2 3x3 (16pad->16) + bias + PReLU, MFMA 16x16x32 bf16.
// R8: address-math diet. Static audit showed ~290 VALU ops/wave vs 100 cyc
// MFMA (VALU-bound staging, m33 signature). Exact-math changes:
//  - s<4: NO clamps. Valid px (<357) have iw=px+kw<=358 in-bounds; ih<=358
//    always. OOB reads (<=~900 B past p16, inside ws) only feed DISCARDED
//    MFMA columns — column independence keeps stored outputs bit-identical.
//  - s=4 pad tap (tap 9): A-frag is zero (repack), so B only needs to be
//    FINITE: one pointer-cndmask to p16 base replaces 64 per-element
//    cndmasks. Contribution exactly 0 == old zf path.
//  - one base address per K-step; 4 tile loads at imm offsets 0/512/1024/1536.
// grid: (6, 90, 16), block 256. No barriers.
// ---------------------------------------------------------------------------
__global__ __launch_bounds__(256)
void conv2_mfma_kernel(const __hip_bfloat16* __restrict__ p16,
                       const float* __restrict__ ws,
                       const float* __restrict__ b2,
                       const float* __restrict__ a2,
                       __hip_bfloat16* __restrict__ c2h) {
    int wv = threadIdx.x >> 6;
    int l  = threadIdx.x & 63;
    int oh  = blockIdx.y * 4 + wv;
    int ow0 = blockIdx.x * 64;
    int n   = blockIdx.z;
    if (oh >= H2) return;

    int pxl = l & 15;          // B col: px within tile
    int q   = l >> 4;
    int taph = q >> 1;         // which tap within K-step (0: lanes<32, 1: >=32)
    int choff = (q & 1) << 3;  // channel sub-chunk

    const bf16x8* aw = (const bf16x8*)(ws + AW2_OFF);
    bf16x8 afr[5];
    #pragma unroll
    for (int s = 0; s < 5; s++) afr[s] = aw[s * 64 + l];

    f32x4 acc[4];
    #pragma unroll
    for (int t = 0; t < 4; t++)
        #pragma unroll
        for (int i = 0; i < 4; i++) acc[t][i] = 0.f;

    #pragma unroll
    for (int s = 0; s < 5; s++) {
        int tap = 2 * s + taph;           // constant-per-half; folds to cndmask
        int kh = tap / 3, kw = tap - kh * 3;
        int ih = oh + kh;                 // <= 358 for real taps; pad tap redirected
        int col = ow0 + pxl + kw;
        int off = ((n * PH + ih) * PH + col) * 16 + choff;  // bf16 elements
        const bf16x8* bp = (const bf16x8*)(p16 + off);
        if (s == 4) {
            // tap 9 (taph=1): A-frag is all-zero; just need finite B.
            bp = taph ? (const bf16x8*)(p16 + choff) : bp;
        }
        acc[0] = __builtin_amdgcn_mfma_f32_16x16x32_bf16(afr[s], bp[0],  acc[0], 0, 0, 0);
        acc[1] = __builtin_amdgcn_mfma_f32_16x16x32_bf16(afr[s], bp[32], acc[1], 0, 0, 0);
        acc[2] = __builtin_amdgcn_mfma_f32_16x16x32_bf16(afr[s], bp[64], acc[2], 0, 0, 0);
        acc[3] = __builtin_amdgcn_mfma_f32_16x16x32_bf16(afr[s], bp[96], acc[3], 0, 0, 0);
    }

    // epilogue: bias+PReLU; lane's elements are (c_out = q*4+r, px = pxl)
    float bb[4], aa[4];
    #pragma unroll
    for (int r = 0; r < 4; r++) { bb[r] = b2[q * 4 + r]; aa[r] = a2[q * 4 + r]; }

    #pragma unroll
    for (int t = 0; t < 4; t++) {
        int px = ow0 + t * 16 + pxl;
        if (px < H2) {
            ushort4v pk;
            #pragma unroll
            for (int r = 0; r < 4; r++) {
                float v = acc[t][r] + bb[r];
                v = v >= 0.f ? v : aa[r] * v;
                __hip_bfloat16 h = __float2bfloat16(v);
                pk[r] = *(unsigned short*)&h;
            }
            *(ushort4v*)(c2h + (((size_t)n * H2 + oh) * H2 + px) * 16 + q * 4) = pk;
        }
    }
}

// ---------------------------------------------------------------------------
// Stage 3: conv3 3x3 (16->32) + PReLU + heads, MFMA 32x32x16 bf16.
// R6b (verified): row-load dedup — 4 distinct rows x 3 kw = 12 loads (was 18)
// in registers ar0..ar3; next-row loads issue between MFMA clusters.
// A = pixels, B = weights; heads via stride-33 LDS; softmax.
// grid: (12, 45, 16), block 256
// ---------------------------------------------------------------------------
__global__ __launch_bounds__(256, 1)
void conv3_heads_kernel(const __hip_bfloat16* __restrict__ c2h,
                        const float* __restrict__ ws,
                        const float* __restrict__ b3,
                        const float* __restrict__ a3,
                        const float* __restrict__ w41,
                        const float* __restrict__ b41,
                        const float* __restrict__ w42,
                        const float* __restrict__ b42,
                        float* __restrict__ out) {
    int wv = threadIdx.x >> 6;
    int l  = threadIdx.x & 63;
    int ow0 = blockIdx.x * 32;
    int oh0 = blockIdx.y * 8 + wv * 2;
    int n   = blockIdx.z;

    int m    = l & 31;
    int half = l >> 5;
    int choff = half << 3;

    const bf16x8* bw = (const bf16x8*)(ws + BW3_OFF);
    bf16x8 bfr[9];
    #pragma unroll
    for (int t = 0; t < 9; t++) bfr[t] = bw[t * 64 + l];

    f32x16 acc0, acc1;
    #pragma unroll
    for (int i = 0; i < 16; i++) { acc0[i] = 0.f; acc1[i] = 0.f; }

    // clamped row/col indices (same clamping as verified version)
    int row0 = oh0;     if (row0 > H2 - 1) row0 = H2 - 1;
    int row1 = oh0 + 1; if (row1 > H2 - 1) row1 = H2 - 1;
    int row2 = oh0 + 2; if (row2 > H2 - 1) row2 = H2 - 1;
    int row3 = oh0 + 3; if (row3 > H2 - 1) row3 = H2 - 1;
    int iwc[3];
    #pragma unroll
    for (int kw = 0; kw < 3; kw++) {
        int iw = ow0 + m + kw; if (iw > H2 - 1) iw = H2 - 1;
        iwc[kw] = iw;
    }

#define LD_ROW(dst, r)                                                          \
    {                                                                           \
        const size_t rb = (((size_t)n * H2 + (r)) * H2);                        \
        dst[0] = *(const bf16x8*)(c2h + ((rb + iwc[0]) << 4) + choff);          \
        dst[1] = *(const bf16x8*)(c2h + ((rb + iwc[1]) << 4) + choff);          \
        dst[2] = *(const bf16x8*)(c2h + ((rb + iwc[2]) << 4) + choff);          \
    }

    bf16x8 ar0[3], ar1[3], ar2[3], ar3[3];
    LD_ROW(ar0, row0);
    LD_ROW(ar1, row1);
    // kh = 0: acc0 uses row0, acc1 uses row1, taps 0..2
    acc0 = __builtin_amdgcn_mfma_f32_32x32x16_bf16(ar0[0], bfr[0], acc0, 0, 0, 0);
    acc1 = __builtin_amdgcn_mfma_f32_32x32x16_bf16(ar1[0], bfr[0], acc1, 0, 0, 0);
    acc0 = __builtin_amdgcn_mfma_f32_32x32x16_bf16(ar0[1], bfr[1], acc0, 0, 0, 0);
    acc1 = __builtin_amdgcn_mfma_f32_32x32x16_bf16(ar1[1], bfr[1], acc1, 0, 0, 0);
    acc0 = __builtin_amdgcn_mfma_f32_32x32x16_bf16(ar0[2], bfr[2], acc0, 0, 0, 0);
    acc1 = __builtin_amdgcn_mfma_f32_32x32x16_bf16(ar1[2], bfr[2], acc1, 0, 0, 0);
    LD_ROW(ar2, row2);
    // kh = 1: acc0 uses row1, acc1 uses row2, taps 3..5
    acc0 = __builtin_amdgcn_mfma_f32_32x32x16_bf16(ar1[0], bfr[3], acc0, 0, 0, 0);
    acc1 = __builtin_amdgcn_mfma_f32_32x32x16_bf16(ar2[0], bfr[3], acc1, 0, 0, 0);
    acc0 = __builtin_amdgcn_mfma_f32_32x32x16_bf16(ar1[1], bfr[4], acc0, 0, 0, 0);
    acc1 = __builtin_amdgcn_mfma_f32_32x32x16_bf16(ar2[1], bfr[4], acc1, 0, 0, 0);
    acc0 = __builtin_amdgcn_mfma_f32_32x32x16_bf16(ar1[2], bfr[5], acc0, 0, 0, 0);
    acc1 = __builtin_amdgcn_mfma_f32_32x32x16_bf16(ar2[2], bfr[5], acc1, 0, 0, 0);
    LD_ROW(ar3, row3);
    // kh = 2: acc0 uses row2, acc1 uses row3, taps 6..8
    acc0 = __builtin_amdgcn_mfma_f32_32x32x16_bf16(ar2[0], bfr[6], acc0, 0, 0, 0);
    acc1 = __builtin_amdgcn_mfma_f32_32x32x16_bf16(ar3[0], bfr[6], acc1, 0, 0, 0);
    acc0 = __builtin_amdgcn_mfma_f32_32x32x16_bf16(ar2[1], bfr[7], acc0, 0, 0, 0);
    acc1 = __builtin_amdgcn_mfma_f32_32x32x16_bf16(ar3[1], bfr[7], acc1, 0, 0, 0);
    acc0 = __builtin_amdgcn_mfma_f32_32x32x16_bf16(ar2[2], bfr[8], acc0, 0, 0, 0);
    acc1 = __builtin_amdgcn_mfma_f32_32x32x16_bf16(ar3[2], bfr[8], acc1, 0, 0, 0);
#undef LD_ROW

    __shared__ float hbuf[4][64 * 33];
    float* hb = hbuf[wv];
    float bb = b3[m], aa = a3[m];
    #pragma unroll
    for (int t = 0; t < 2; t++) {
        #pragma unroll
        for (int r = 0; r < 16; r++) {
            int mprime = (r & 3) + ((r >> 2) << 3) + (half << 2);
            float v = (t ? acc1[r] : acc0[r]) + bb;
            v = v >= 0.f ? v : aa * v;
            hb[(t * 32 + mprime) * 33 + m] = v;
        }
    }
    __syncthreads();

    int poh = oh0 + (l >> 5);
    int pow_ = ow0 + (l & 31);
    float h[32];
    #pragma unroll
    for (int c = 0; c < 32; c++) h[c] = hb[l * 33 + c];

    float l0 = b41[0], l1 = b41[1];
    float r0 = b42[0], r1 = b42[1], r2 = b42[2], r3 = b42[3];
    #pragma unroll
    for (int c = 0; c < 32; c++) {
        float hv = h[c];
        l0 = fmaf(hv, w41[c],      l0);
        l1 = fmaf(hv, w41[32 + c], l1);
        r0 = fmaf(hv, w42[c],      r0);
        r1 = fmaf(hv, w42[32 + c], r1);
        r2 = fmaf(hv, w42[64 + c], r2);
        r3 = fmaf(hv, w42[96 + c], r3);
    }
    float mx  = fmaxf(l0, l1);
    float e0 = __expf(l0 - mx), e1 = __expf(l1 - mx);
    float inv = 1.0f / (e0 + e1);

    if (poh < H3 && pow_ < H3) {
        const size_t sp = (size_t)H3 * H3;
        size_t pos = (size_t)poh * H3 + pow_;
        float* reg  = out;
        float* prob = out + (size_t)16 * 4 * sp;
        reg[((size_t)(n * 4 + 0)) * sp + pos] = r0;
        reg[((size_t)(n * 4 + 1)) * sp + pos] = r1;
        reg[((size_t)(n * 4 + 2)) * sp + pos] = r2;
        reg[((size_t)(n * 4 + 3)) * sp + pos] = r3;
        prob[((size_t)(n * 2 + 0)) * sp + pos] = e0 * inv;
        prob[((size_t)(n * 2 + 1)) * sp + pos] = e1 * inv;
    }
}

extern "C" void kernel_launch(void* const* d_in, const int* in_sizes, int n_in,
                              void* d_out, int out_size, void* d_ws, size_t ws_size,
                              hipStream_t stream) {
    const float* x   = (const float*)d_in[0];
    const float* w1  = (const float*)d_in[1];
    const float* b1  = (const float*)d_in[2];
    const float* a1  = (const float*)d_in[3];
    const float* w2  = (const float*)d_in[4];
    const float* b2  = (const float*)d_in[5];
    const float* a2  = (const float*)d_in[6];
    const float* w3  = (const float*)d_in[7];
    const float* b3  = (const float*)d_in[8];
    const float* a3  = (const float*)d_in[9];
    const float* w41 = (const float*)d_in[10];
    const float* b41 = (const float*)d_in[11];
    const float* w42 = (const float*)d_in[12];
    const float* b42 = (const float*)d_in[13];
    float* out = (float*)d_out;
    float* ws  = (float*)d_ws;

    __hip_bfloat16* p16 = (__hip_bfloat16*)(ws + P16_OFF);
    __hip_bfloat16* c2h = (__hip_bfloat16*)(ws + C2H_OFF);

    repack_kernel<<<29, 256, 0, stream>>>(w1, b1, w2, w3, ws);

    {
        dim3 grid((PH + 127) / 128, PH, 16);
        conv1_pool_kernel<<<grid, 128, 0, stream>>>(x, ws, a1, p16);
    }
    {
        dim3 grid((H2 + 63) / 64, (H2 + 3) / 4, 16);
        conv2_mfma_kernel<<<grid, 256, 0, stream>>>(p16, ws, b2, a2, c2h);
    }
    {
        dim3 grid((H3 + 31) / 32, (H3 + 7) / 8, 16);
        conv3_heads_kernel<<<grid, 256, 0, stream>>>(c2h, ws, b3, a3,
                                                     w41, b41, w42, b42, out);
    }
}

// Round 9
// 294.885 us; speedup vs baseline: 1.1661x; 1.0388x over previous
//
#include <hip/hip_runtime.h>
#include <hip/hip_bf16.h>
#include <cstddef>

// ---------------------------------------------------------------------------
// MTCNN P-Net forward, NCHW in/out.
//   x[16,3,720,720] -> norm -> conv1(3->10,3x3)+PReLU -> maxpool2 (fp32 math)
//     -> pooled NHWC bf16 (padded 10->16 ch)
//     -> conv2(16->16,3x3) via MFMA 16x16x32 bf16 -> NHWC bf16
//     -> conv3(16->32,3x3)+PReLU via MFMA 32x32x16 bf16, fused heads
//   out = concat(reg[16,4,355,355], prob[16,2,355,355]) flat fp32
// ---------------------------------------------------------------------------

#define H1 718
#define PH 359   // pooled spatial
#define H2 357   // conv2 out spatial
#define H3 355   // conv3 out spatial

// workspace layout (float offsets)
#define W1R_OFF 0              // 270 fp32, pre-scaled by 1/128
#define B1R_OFF 288            // 10 fp32 (norm folded in)
#define AW2_OFF 320            // 2560 bf16 = 1280 fl: conv2 A-frags [step][lane][8]
#define BW3_OFF 1600           // 4608 bf16 = 2304 fl: conv3 B-frags [tap][lane][8]
#define P16_OFF 4096           // pooled NHWC bf16 [16,359,359,16] = 16496768 fl
#define C2H_OFF 16500864       // conv2 out NHWC bf16 [16,357,357,16] = 16313472 fl

typedef short bf16x8 __attribute__((ext_vector_type(8)));
typedef float f32x4  __attribute__((ext_vector_type(4)));
typedef float f32x16 __attribute__((ext_vector_type(16)));
typedef unsigned short ushort4v __attribute__((ext_vector_type(4)));

// ---------------------------------------------------------------------------
// Weight repack — parallelized across 29 blocks (R6; verified).
// ---------------------------------------------------------------------------
__global__ void repack_kernel(const float* __restrict__ w1, const float* __restrict__ b1,
                              const float* __restrict__ w2, const float* __restrict__ w3,
                              float* __restrict__ ws) {
    int t = threadIdx.x;
    int bid = blockIdx.x;
    if (bid == 0) {
        const float S = 0.0078125f;
        for (int i = t; i < 270; i += 256) ws[W1R_OFF + i] = w1[i] * S;
        if (t < 10) {
            float s = 0.f;
            for (int i = 0; i < 27; i++) s += w1[t * 27 + i];
            ws[B1R_OFF + t] = b1[t] - 127.5f * S * s;
        }
    } else if (bid <= 10) {
        int e = (bid - 1) * 256 + t;  // 0..2559
        unsigned short* aw2 = (unsigned short*)(ws + AW2_OFF);
        int s = e >> 9;              // K-step 0..4
        int rem = e & 511;
        int l = rem >> 3, j = rem & 7;
        int q = l >> 4, co = l & 15;
        int tap = 2 * s + (q >> 1);
        int ci  = ((q & 1) << 3) + j;
        float v = (tap < 9 && ci < 10) ? w2[co * 90 + ci * 9 + tap] : 0.f;
        __hip_bfloat16 h = __float2bfloat16(v);
        aw2[e] = *(unsigned short*)&h;
    } else {
        int e = (bid - 11) * 256 + t; // 0..4607
        unsigned short* bw3 = (unsigned short*)(ws + BW3_OFF);
        int tap = e >> 9;
        int rem = e & 511;
        int l = rem >> 3, j = rem & 7;
        int kh = tap / 3, kw = tap % 3;
        int co = l & 31, ci = ((l >> 5) << 3) + j;
        float v = w3[co * 144 + ci * 9 + kh * 3 + kw];
        __hip_bfloat16 h = __float2bfloat16(v);
        bw3[e] = *(unsigned short*)&h;
    }
}

// ---------------------------------------------------------------------------
// Stage 1: norm+conv1+PReLU+maxpool fused, all 10 channels per thread.
// EXACT R0 body. R9: n_base parameter so the launch is SPLIT into two z=8
// dispatches (~38 us each) — purely so conv2/conv3 surface in the rocprof
// top-5 next round (they've been hidden behind conv1's 76 us all session).
// grid: (3, 359, 8) x2, block 128.
// ---------------------------------------------------------------------------
__global__ void conv1_pool_kernel(const float* __restrict__ x,
                                  const float* __restrict__ ws,
                                  const float* __restrict__ a1,
                                  __hip_bfloat16* __restrict__ p16,
                                  int n_base) {
    int pw = blockIdx.x * blockDim.x + threadIdx.x;
    int ph = blockIdx.y;
    int n  = blockIdx.z + n_base;
    if (pw >= PH) return;
    int iy = 2 * ph, ix = 2 * pw;

    float acc[10][4];
    #pragma unroll
    for (int c = 0; c < 10; c++)
        #pragma unroll
        for (int p = 0; p < 4; p++) acc[c][p] = 0.f;

    #pragma unroll
    for (int ci = 0; ci < 3; ci++) {
        const float* xp = x + (((size_t)(n * 3 + ci) * 720 + iy) * 720 + ix);
        float win[4][4];
        #pragma unroll
        for (int r = 0; r < 4; r++) {
            float2 v0 = *(const float2*)(xp + r * 720);
            float2 v1 = *(const float2*)(xp + r * 720 + 2);
            win[r][0] = v0.x; win[r][1] = v0.y; win[r][2] = v1.x; win[r][3] = v1.y;
        }
        #pragma unroll
        for (int c = 0; c < 10; c++) {
            const float* wk = ws + W1R_OFF + c * 27 + ci * 9;
            #pragma unroll
            for (int kh = 0; kh < 3; kh++)
                #pragma unroll
                for (int kw = 0; kw < 3; kw++) {
                    float wv = wk[kh * 3 + kw];
                    acc[c][0] = fmaf(win[kh    ][kw    ], wv, acc[c][0]);
                    acc[c][1] = fmaf(win[kh    ][kw + 1], wv, acc[c][1]);
                    acc[c][2] = fmaf(win[kh + 1][kw    ], wv, acc[c][2]);
                    acc[c][3] = fmaf(win[kh + 1][kw + 1], wv, acc[c][3]);
                }
        }
    }

    __hip_bfloat16 o[16];
    #pragma unroll
    for (int c = 0; c < 10; c++) {
        float b = ws[B1R_OFF + c], al = a1[c];
        float s0 = acc[c][0] + b, s1 = acc[c][1] + b;
        float s2 = acc[c][2] + b, s3 = acc[c][3] + b;
        s0 = s0 >= 0.f ? s0 : al * s0;
        s1 = s1 >= 0.f ? s1 : al * s1;
        s2 = s2 >= 0.f ? s2 : al * s2;
        s3 = s3 >= 0.f ? s3 : al * s3;
        o[c] = __float2bfloat16(fmaxf(fmaxf(s0, s1), fmaxf(s2, s3)));
    }
    #pragma unroll
    for (int c = 10; c < 16; c++) o[c] = __float2bfloat16(0.f);

    float4* dst = (float4*)(p16 + (((size_t)n * PH + ph) * PH + pw) * 16);
    dst[0] = ((float4*)o)[0];
    dst[1] = ((float4*)o)[1];
}

// ---------------------------------------------------------------------------
// Stage 2: conv2 3x3 (16pad->16) + bias + PReLU, MFMA 16x16x32 bf16.
// R8 diet (verified) + R9 XCD-aware block swizzle:
// linear dispatch round-robins x-neighbor tiles (sharing p16 rows) across
// 8 XCD L2s -> every L2 re-fetches the same rows from L3 (p16 is L3-resident,
// FETCH stays low but latency is L2-miss). Bijective swizzle (8640%8==0,
// chunk 1080) gives each XCD a contiguous ~2-batch run: neighbor tiles on
// the same L2. Pure remap, no correctness surface.
// grid: 8640 flat, block 256. No barriers.
// ---------------------------------------------------------------------------
__global__ __launch_bounds__(256)
void conv2_mfma_kernel(const __hip_bfloat16* __restrict__ p16,
                       const float* __restrict__ ws,
                       const float* __restrict__ b2,
                       const float* __restrict__ a2,
                       __hip_bfloat16* __restrict__ c2h) {
    // XCD swizzle: flat -> (bx, by, n)
    int flat = blockIdx.x;                     // 0..8639
    int swz  = (flat & 7) * 1080 + (flat >> 3);
    int n    = swz / 540;                      // 540 = 6*90 blocks per batch
    int rem  = swz - n * 540;
    int by   = rem / 6;
    int bx   = rem - by * 6;

    int wv = threadIdx.x >> 6;
    int l  = threadIdx.x & 63;
    int oh  = by * 4 + wv;
    int ow0 = bx * 64;
    if (oh >= H2) return;

    int pxl = l & 15;          // B col: px within tile
    int q   = l >> 4;
    int taph = q >> 1;         // which tap within K-step (0: lanes<32, 1: >=32)
    int choff = (q & 1) << 3;  // channel sub-chunk

    const bf16x8* aw = (const bf16x8*)(ws + AW2_OFF);
    bf16x8 afr[5];
    #pragma unroll
    for (int s = 0; s < 5; s++) afr[s] = aw[s * 64 + l];

    f32x4 acc[4];
    #pragma unroll
    for (int t = 0; t < 4; t++)
        #pragma unroll
        for (int i = 0; i < 4; i++) acc[t][i] = 0.f;

    #pragma unroll
    for (int s = 0; s < 5; s++) {
        int tap = 2 * s + taph;           // constant-per-half; folds to cndmask
        int kh = tap / 3, kw = tap - kh * 3;
        int ih = oh + kh;                 // <= 358 for real taps; pad tap redirected
        int col = ow0 + pxl + kw;
        int off = ((n * PH + ih) * PH + col) * 16 + choff;  // bf16 elements
        const bf16x8* bp = (const bf16x8*)(p16 + off);
        if (s == 4) {
            // tap 9 (taph=1): A-frag is all-zero; just need finite B.
            bp = taph ? (const bf16x8*)(p16 + choff) : bp;
        }
        acc[0] = __builtin_amdgcn_mfma_f32_16x16x32_bf16(afr[s], bp[0],  acc[0], 0, 0, 0);
        acc[1] = __builtin_amdgcn_mfma_f32_16x16x32_bf16(afr[s], bp[32], acc[1], 0, 0, 0);
        acc[2] = __builtin_amdgcn_mfma_f32_16x16x32_bf16(afr[s], bp[64], acc[2], 0, 0, 0);
        acc[3] = __builtin_amdgcn_mfma_f32_16x16x32_bf16(afr[s], bp[96], acc[3], 0, 0, 0);
    }

    // epilogue: bias+PReLU; lane's elements are (c_out = q*4+r, px = pxl)
    float bb[4], aa[4];
    #pragma unroll
    for (int r = 0; r < 4; r++) { bb[r] = b2[q * 4 + r]; aa[r] = a2[q * 4 + r]; }

    #pragma unroll
    for (int t = 0; t < 4; t++) {
        int px = ow0 + t * 16 + pxl;
        if (px < H2) {
            ushort4v pk;
            #pragma unroll
            for (int r = 0; r < 4; r++) {
                float v = acc[t][r] + bb[r];
                v = v >= 0.f ? v : aa[r] * v;
                __hip_bfloat16 h = __float2bfloat16(v);
                pk[r] = *(unsigned short*)&h;
            }
            *(ushort4v*)(c2h + (((size_t)n * H2 + oh) * H2 + px) * 16 + q * 4) = pk;
        }
    }
}

// ---------------------------------------------------------------------------
// Stage 3: conv3 3x3 (16->32) + PReLU + heads, MFMA 32x32x16 bf16.
// R6b row-dedup (verified) + R9 XCD-aware block swizzle (same rationale as
// conv2: c2h is L3-resident; neighbor tiles share rows -> keep them on one
// XCD's L2). grid: 8640 flat, block 256.
// ---------------------------------------------------------------------------
__global__ __launch_bounds__(256, 1)
void conv3_heads_kernel(const __hip_bfloat16* __restrict__ c2h,
                        const float* __restrict__ ws,
                        const float* __restrict__ b3,
                        const float* __restrict__ a3,
                        const float* __restrict__ w41,
                        const float* __restrict__ b41,
                        const float* __restrict__ w42,
                        const float* __restrict__ b42,
                        float* __restrict__ out) {
    // XCD swizzle: flat -> (bx, by, n); 540 = 12*45 blocks per batch
    int flat = blockIdx.x;
    int swz  = (flat & 7) * 1080 + (flat >> 3);
    int n    = swz / 540;
    int rem  = swz - n * 540;
    int by   = rem / 12;
    int bx   = rem - by * 12;

    int wv = threadIdx.x >> 6;
    int l  = threadIdx.x & 63;
    int ow0 = bx * 32;
    int oh0 = by * 8 + wv * 2;

    int m    = l & 31;
    int half = l >> 5;
    int choff = half << 3;

    const bf16x8* bw = (const bf16x8*)(ws + BW3_OFF);
    bf16x8 bfr[9];
    #pragma unroll
    for (int t = 0; t < 9; t++) bfr[t] = bw[t * 64 + l];

    f32x16 acc0, acc1;
    #pragma unroll
    for (int i = 0; i < 16; i++) { acc0[i] = 0.f; acc1[i] = 0.f; }

    // clamped row/col indices (same clamping as verified version)
    int row0 = oh0;     if (row0 > H2 - 1) row0 = H2 - 1;
    int row1 = oh0 + 1; if (row1 > H2 - 1) row1 = H2 - 1;
    int row2 = oh0 + 2; if (row2 > H2 - 1) row2 = H2 - 1;
    int row3 = oh0 + 3; if (row3 > H2 - 1) row3 = H2 - 1;
    int iwc[3];
    #pragma unroll
    for (int kw = 0; kw < 3; kw++) {
        int iw = ow0 + m + kw; if (iw > H2 - 1) iw = H2 - 1;
        iwc[kw] = iw;
    }

#define LD_ROW(dst, r)                                                          \
    {                                                                           \
        const size_t rb = (((size_t)n * H2 + (r)) * H2);                        \
        dst[0] = *(const bf16x8*)(c2h + ((rb + iwc[0]) << 4) + choff);          \
        dst[1] = *(const bf16x8*)(c2h + ((rb + iwc[1]) << 4) + choff);          \
        dst[2] = *(const bf16x8*)(c2h + ((rb + iwc[2]) << 4) + choff);          \
    }

    bf16x8 ar0[3], ar1[3], ar2[3], ar3[3];
    LD_ROW(ar0, row0);
    LD_ROW(ar1, row1);
    // kh = 0: acc0 uses row0, acc1 uses row1, taps 0..2
    acc0 = __builtin_amdgcn_mfma_f32_32x32x16_bf16(ar0[0], bfr[0], acc0, 0, 0, 0);
    acc1 = __builtin_amdgcn_mfma_f32_32x32x16_bf16(ar1[0], bfr[0], acc1, 0, 0, 0);
    acc0 = __builtin_amdgcn_mfma_f32_32x32x16_bf16(ar0[1], bfr[1], acc0, 0, 0, 0);
    acc1 = __builtin_amdgcn_mfma_f32_32x32x16_bf16(ar1[1], bfr[1], acc1, 0, 0, 0);
    acc0 = __builtin_amdgcn_mfma_f32_32x32x16_bf16(ar0[2], bfr[2], acc0, 0, 0, 0);
    acc1 = __builtin_amdgcn_mfma_f32_32x32x16_bf16(ar1[2], bfr[2], acc1, 0, 0, 0);
    LD_ROW(ar2, row2);
    // kh = 1: acc0 uses row1, acc1 uses row2, taps 3..5
    acc0 = __builtin_amdgcn_mfma_f32_32x32x16_bf16(ar1[0], bfr[3], acc0, 0, 0, 0);
    acc1 = __builtin_amdgcn_mfma_f32_32x32x16_bf16(ar2[0], bfr[3], acc1, 0, 0, 0);
    acc0 = __builtin_amdgcn_mfma_f32_32x32x16_bf16(ar1[1], bfr[4], acc0, 0, 0, 0);
    acc1 = __builtin_amdgcn_mfma_f32_32x32x16_bf16(ar2[1], bfr[4], acc1, 0, 0, 0);
    acc0 = __builtin_amdgcn_mfma_f32_32x32x16_bf16(ar1[2], bfr[5], acc0, 0, 0, 0);
    acc1 = __builtin_amdgcn_mfma_f32_32x32x16_bf16(ar2[2], bfr[5], acc1, 0, 0, 0);
    LD_ROW(ar3, row3);
    // kh = 2: acc0 uses row2, acc1 uses row3, taps 6..8
    acc0 = __builtin_amdgcn_mfma_f32_32x32x16_bf16(ar2[0], bfr[6], acc0, 0, 0, 0);
    acc1 = __builtin_amdgcn_mfma_f32_32x32x16_bf16(ar3[0], bfr[6], acc1, 0, 0, 0);
    acc0 = __builtin_amdgcn_mfma_f32_32x32x16_bf16(ar2[1], bfr[7], acc0, 0, 0, 0);
    acc1 = __builtin_amdgcn_mfma_f32_32x32x16_bf16(ar3[1], bfr[7], acc1, 0, 0, 0);
    acc0 = __builtin_amdgcn_mfma_f32_32x32x16_bf16(ar2[2], bfr[8], acc0, 0, 0, 0);
    acc1 = __builtin_amdgcn_mfma_f32_32x32x16_bf16(ar3[2], bfr[8], acc1, 0, 0, 0);
#undef LD_ROW

    __shared__ float hbuf[4][64 * 33];
    float* hb = hbuf[wv];
    float bb = b3[m], aa = a3[m];
    #pragma unroll
    for (int t = 0; t < 2; t++) {
        #pragma unroll
        for (int r = 0; r < 16; r++) {
            int mprime = (r & 3) + ((r >> 2) << 3) + (half << 2);
            float v = (t ? acc1[r] : acc0[r]) + bb;
            v = v >= 0.f ? v : aa * v;
            hb[(t * 32 + mprime) * 33 + m] = v;
        }
    }
    __syncthreads();

    int poh = oh0 + (l >> 5);
    int pow_ = ow0 + (l & 31);
    float h[32];
    #pragma unroll
    for (int c = 0; c < 32; c++) h[c] = hb[l * 33 + c];

    float l0 = b41[0], l1 = b41[1];
    float r0 = b42[0], r1 = b42[1], r2 = b42[2], r3 = b42[3];
    #pragma unroll
    for (int c = 0; c < 32; c++) {
        float hv = h[c];
        l0 = fmaf(hv, w41[c],      l0);
        l1 = fmaf(hv, w41[32 + c], l1);
        r0 = fmaf(hv, w42[c],      r0);
        r1 = fmaf(hv, w42[32 + c], r1);
        r2 = fmaf(hv, w42[64 + c], r2);
        r3 = fmaf(hv, w42[96 + c], r3);
    }
    float mx  = fmaxf(l0, l1);
    float e0 = __expf(l0 - mx), e1 = __expf(l1 - mx);
    float inv = 1.0f / (e0 + e1);

    if (poh < H3 && pow_ < H3) {
        const size_t sp = (size_t)H3 * H3;
        size_t pos = (size_t)poh * H3 + pow_;
        float* reg  = out;
        float* prob = out + (size_t)16 * 4 * sp;
        reg[((size_t)(n * 4 + 0)) * sp + pos] = r0;
        reg[((size_t)(n * 4 + 1)) * sp + pos] = r1;
        reg[((size_t)(n * 4 + 2)) * sp + pos] = r2;
        reg[((size_t)(n * 4 + 3)) * sp + pos] = r3;
        prob[((size_t)(n * 2 + 0)) * sp + pos] = e0 * inv;
        prob[((size_t)(n * 2 + 1)) * sp + pos] = e1 * inv;
    }
}

extern "C" void kernel_launch(void* const* d_in, const int* in_sizes, int n_in,
                              void* d_out, int out_size, void* d_ws, size_t ws_size,
                              hipStream_t stream) {
    const float* x   = (const float*)d_in[0];
    const float* w1  = (const float*)d_in[1];
    const float* b1  = (const float*)d_in[2];
    const float* a1  = (const float*)d_in[3];
    const float* w2  = (const float*)d_in[4];
    const float* b2  = (const float*)d_in[5];
    const float* a2  = (const float*)d_in[6];
    const float* w3  = (const float*)d_in[7];
    const float* b3  = (const float*)d_in[8];
    const float* a3  = (const float*)d_in[9];
    const float* w41 = (const float*)d_in[10];
    const float* b41 = (const float*)d_in[11];
    const float* w42 = (const float*)d_in[12];
    const float* b42 = (const float*)d_in[13];
    float* out = (float*)d_out;
    float* ws  = (float*)d_ws;

    __hip_bfloat16* p16 = (__hip_bfloat16*)(ws + P16_OFF);
    __hip_bfloat16* c2h = (__hip_bfloat16*)(ws + C2H_OFF);

    repack_kernel<<<29, 256, 0, stream>>>(w1, b1, w2, w3, ws);

    {
        // split into two z=8 dispatches so conv2/conv3 surface in rocprof top-5
        dim3 grid((PH + 127) / 128, PH, 8);
        conv1_pool_kernel<<<grid, 128, 0, stream>>>(x, ws, a1, p16, 0);
        conv1_pool_kernel<<<grid, 128, 0, stream>>>(x, ws, a1, p16, 8);
    }
    {
        conv2_mfma_kernel<<<8640, 256, 0, stream>>>(p16, ws, b2, a2, c2h);
    }
    {
        conv3_heads_kernel<<<8640, 256, 0, stream>>>(c2h, ws, b3, a3,
                                                     w41, b41, w42, b42, out);
    }
}

// Round 10
// 293.835 us; speedup vs baseline: 1.1703x; 1.0036x over previous
//
#include <hip/hip_runtime.h>
#include <hip/hip_bf16.h>
#include <cstddef>

// ---------------------------------------------------------------------------
// MTCNN P-Net forward, NCHW in/out.
//   x[16,3,720,720] -> norm -> conv1(3->10,3x3)+PReLU -> maxpool2 (fp32 math)
//     -> pooled NHWC bf16 (padded 10->16 ch)
//     -> conv2(16->16,3x3) via MFMA 16x16x32 bf16 -> NHWC bf16
//     -> conv3(16->32,3x3)+PReLU via MFMA 32x32x16 bf16, fused heads
//   out = concat(reg[16,4,355,355], prob[16,2,355,355]) flat fp32
// ---------------------------------------------------------------------------

#define H1 718
#define PH 359   // pooled spatial
#define H2 357   // conv2 out spatial
#define H3 355   // conv3 out spatial

// workspace layout (float offsets)
#define W1R_OFF 0              // 270 fp32, pre-scaled by 1/128
#define B1R_OFF 288            // 10 fp32 (norm folded in)
#define AW2_OFF 320            // 2560 bf16 = 1280 fl: conv2 A-frags [step][lane][8]
#define BW3_OFF 1600           // 4608 bf16 = 2304 fl: conv3 B-frags [tap][lane][8]
#define P16_OFF 4096           // pooled NHWC bf16 [16,359,359,16] = 16496768 fl
#define C2H_OFF 16500864       // conv2 out NHWC bf16 [16,357,357,16] = 16313472 fl

typedef short bf16x8 __attribute__((ext_vector_type(8)));
typedef float f32x4  __attribute__((ext_vector_type(4)));
typedef float f32x16 __attribute__((ext_vector_type(16)));
typedef unsigned short ushort4v __attribute__((ext_vector_type(4)));

// ---------------------------------------------------------------------------
// Weight repack — parallelized across 29 blocks (R6; verified).
// ---------------------------------------------------------------------------
__global__ void repack_kernel(const float* __restrict__ w1, const float* __restrict__ b1,
                              const float* __restrict__ w2, const float* __restrict__ w3,
                              float* __restrict__ ws) {
    int t = threadIdx.x;
    int bid = blockIdx.x;
    if (bid == 0) {
        const float S = 0.0078125f;
        for (int i = t; i < 270; i += 256) ws[W1R_OFF + i] = w1[i] * S;
        if (t < 10) {
            float s = 0.f;
            for (int i = 0; i < 27; i++) s += w1[t * 27 + i];
            ws[B1R_OFF + t] = b1[t] - 127.5f * S * s;
        }
    } else if (bid <= 10) {
        int e = (bid - 1) * 256 + t;  // 0..2559
        unsigned short* aw2 = (unsigned short*)(ws + AW2_OFF);
        int s = e >> 9;              // K-step 0..4
        int rem = e & 511;
        int l = rem >> 3, j = rem & 7;
        int q = l >> 4, co = l & 15;
        int tap = 2 * s + (q >> 1);
        int ci  = ((q & 1) << 3) + j;
        float v = (tap < 9 && ci < 10) ? w2[co * 90 + ci * 9 + tap] : 0.f;
        __hip_bfloat16 h = __float2bfloat16(v);
        aw2[e] = *(unsigned short*)&h;
    } else {
        int e = (bid - 11) * 256 + t; // 0..4607
        unsigned short* bw3 = (unsigned short*)(ws + BW3_OFF);
        int tap = e >> 9;
        int rem = e & 511;
        int l = rem >> 3, j = rem & 7;
        int kh = tap / 3, kw = tap % 3;
        int co = l & 31, ci = ((l >> 5) << 3) + j;
        float v = w3[co * 144 + ci * 9 + kh * 3 + kw];
        __hip_bfloat16 h = __float2bfloat16(v);
        bw3[e] = *(unsigned short*)&h;
    }
}

// ---------------------------------------------------------------------------
// Stage 1: norm+conv1+PReLU+maxpool fused, all 10 channels per thread.
// EXACT R0 body, single dispatch again (R9's z-split was diagnostic-only;
// the rocprof top-5 is saturated by the harness fill kernel regardless).
// grid: (3, 359, 16), block 128.
// ---------------------------------------------------------------------------
__global__ void conv1_pool_kernel(const float* __restrict__ x,
                                  const float* __restrict__ ws,
                                  const float* __restrict__ a1,
                                  __hip_bfloat16* __restrict__ p16) {
    int pw = blockIdx.x * blockDim.x + threadIdx.x;
    int ph = blockIdx.y;
    int n  = blockIdx.z;
    if (pw >= PH) return;
    int iy = 2 * ph, ix = 2 * pw;

    float acc[10][4];
    #pragma unroll
    for (int c = 0; c < 10; c++)
        #pragma unroll
        for (int p = 0; p < 4; p++) acc[c][p] = 0.f;

    #pragma unroll
    for (int ci = 0; ci < 3; ci++) {
        const float* xp = x + (((size_t)(n * 3 + ci) * 720 + iy) * 720 + ix);
        float win[4][4];
        #pragma unroll
        for (int r = 0; r < 4; r++) {
            float2 v0 = *(const float2*)(xp + r * 720);
            float2 v1 = *(const float2*)(xp + r * 720 + 2);
            win[r][0] = v0.x; win[r][1] = v0.y; win[r][2] = v1.x; win[r][3] = v1.y;
        }
        #pragma unroll
        for (int c = 0; c < 10; c++) {
            const float* wk = ws + W1R_OFF + c * 27 + ci * 9;
            #pragma unroll
            for (int kh = 0; kh < 3; kh++)
                #pragma unroll
                for (int kw = 0; kw < 3; kw++) {
                    float wv = wk[kh * 3 + kw];
                    acc[c][0] = fmaf(win[kh    ][kw    ], wv, acc[c][0]);
                    acc[c][1] = fmaf(win[kh    ][kw + 1], wv, acc[c][1]);
                    acc[c][2] = fmaf(win[kh + 1][kw    ], wv, acc[c][2]);
                    acc[c][3] = fmaf(win[kh + 1][kw + 1], wv, acc[c][3]);
                }
        }
    }

    __hip_bfloat16 o[16];
    #pragma unroll
    for (int c = 0; c < 10; c++) {
        float b = ws[B1R_OFF + c], al = a1[c];
        float s0 = acc[c][0] + b, s1 = acc[c][1] + b;
        float s2 = acc[c][2] + b, s3 = acc[c][3] + b;
        s0 = s0 >= 0.f ? s0 : al * s0;
        s1 = s1 >= 0.f ? s1 : al * s1;
        s2 = s2 >= 0.f ? s2 : al * s2;
        s3 = s3 >= 0.f ? s3 : al * s3;
        o[c] = __float2bfloat16(fmaxf(fmaxf(s0, s1), fmaxf(s2, s3)));
    }
    #pragma unroll
    for (int c = 10; c < 16; c++) o[c] = __float2bfloat16(0.f);

    float4* dst = (float4*)(p16 + (((size_t)n * PH + ph) * PH + pw) * 16);
    dst[0] = ((float4*)o)[0];
    dst[1] = ((float4*)o)[1];
}

// ---------------------------------------------------------------------------
// Stage 2: conv2 3x3 (16pad->16) + bias + PReLU, MFMA 16x16x32 bf16.
// R8 diet + R9 XCD swizzle (both verified; swizzle netted −11 us with conv3).
// grid: 8640 flat, block 256. No barriers.
// ---------------------------------------------------------------------------
__global__ __launch_bounds__(256)
void conv2_mfma_kernel(const __hip_bfloat16* __restrict__ p16,
                       const float* __restrict__ ws,
                       const float* __restrict__ b2,
                       const float* __restrict__ a2,
                       __hip_bfloat16* __restrict__ c2h) {
    // XCD swizzle: flat -> (bx, by, n)
    int flat = blockIdx.x;                     // 0..8639
    int swz  = (flat & 7) * 1080 + (flat >> 3);
    int n    = swz / 540;                      // 540 = 6*90 blocks per batch
    int rem  = swz - n * 540;
    int by   = rem / 6;
    int bx   = rem - by * 6;

    int wv = threadIdx.x >> 6;
    int l  = threadIdx.x & 63;
    int oh  = by * 4 + wv;
    int ow0 = bx * 64;
    if (oh >= H2) return;

    int pxl = l & 15;          // B col: px within tile
    int q   = l >> 4;
    int taph = q >> 1;         // which tap within K-step (0: lanes<32, 1: >=32)
    int choff = (q & 1) << 3;  // channel sub-chunk

    const bf16x8* aw = (const bf16x8*)(ws + AW2_OFF);
    bf16x8 afr[5];
    #pragma unroll
    for (int s = 0; s < 5; s++) afr[s] = aw[s * 64 + l];

    f32x4 acc[4];
    #pragma unroll
    for (int t = 0; t < 4; t++)
        #pragma unroll
        for (int i = 0; i < 4; i++) acc[t][i] = 0.f;

    #pragma unroll
    for (int s = 0; s < 5; s++) {
        int tap = 2 * s + taph;           // constant-per-half; folds to cndmask
        int kh = tap / 3, kw = tap - kh * 3;
        int ih = oh + kh;                 // <= 358 for real taps; pad tap redirected
        int col = ow0 + pxl + kw;
        int off = ((n * PH + ih) * PH + col) * 16 + choff;  // bf16 elements
        const bf16x8* bp = (const bf16x8*)(p16 + off);
        if (s == 4) {
            // tap 9 (taph=1): A-frag is all-zero; just need finite B.
            bp = taph ? (const bf16x8*)(p16 + choff) : bp;
        }
        acc[0] = __builtin_amdgcn_mfma_f32_16x16x32_bf16(afr[s], bp[0],  acc[0], 0, 0, 0);
        acc[1] = __builtin_amdgcn_mfma_f32_16x16x32_bf16(afr[s], bp[32], acc[1], 0, 0, 0);
        acc[2] = __builtin_amdgcn_mfma_f32_16x16x32_bf16(afr[s], bp[64], acc[2], 0, 0, 0);
        acc[3] = __builtin_amdgcn_mfma_f32_16x16x32_bf16(afr[s], bp[96], acc[3], 0, 0, 0);
    }

    // epilogue: bias+PReLU; lane's elements are (c_out = q*4+r, px = pxl)
    float bb[4], aa[4];
    #pragma unroll
    for (int r = 0; r < 4; r++) { bb[r] = b2[q * 4 + r]; aa[r] = a2[q * 4 + r]; }

    #pragma unroll
    for (int t = 0; t < 4; t++) {
        int px = ow0 + t * 16 + pxl;
        if (px < H2) {
            ushort4v pk;
            #pragma unroll
            for (int r = 0; r < 4; r++) {
                float v = acc[t][r] + bb[r];
                v = v >= 0.f ? v : aa[r] * v;
                __hip_bfloat16 h = __float2bfloat16(v);
                pk[r] = *(unsigned short*)&h;
            }
            *(ushort4v*)(c2h + (((size_t)n * H2 + oh) * H2 + px) * 16 + q * 4) = pk;
        }
    }
}

// ---------------------------------------------------------------------------
// Stage 3: conv3 3x3 (16->32) + PReLU + heads, MFMA 32x32x16 bf16.
// R10: occupancy fix. Issue-work arithmetic says ~11 us; conv3 runs ~50 us
// -> ~80% memory-latency stall. (256,1) gave the allocator a 512-VGPR budget
// (live set ~130-150 -> ~3 waves/SIMD; 12 scattered 16 B row-loads/lane at
// L2/L3 latency can't be hidden).
//   - __launch_bounds__(256, 4): 128-VGPR cap -> 4 waves/SIMD
//   - B-frags loaded per-kh (3 at a time, same loads/values/order ->
//     bit-identical) to cut peak live by ~24 VGPR so the cap doesn't spill
// R6b row-dedup + R9 XCD swizzle kept. grid: 8640 flat, block 256.
// ---------------------------------------------------------------------------
__global__ __launch_bounds__(256, 4)
void conv3_heads_kernel(const __hip_bfloat16* __restrict__ c2h,
                        const float* __restrict__ ws,
                        const float* __restrict__ b3,
                        const float* __restrict__ a3,
                        const float* __restrict__ w41,
                        const float* __restrict__ b41,
                        const float* __restrict__ w42,
                        const float* __restrict__ b42,
                        float* __restrict__ out) {
    // XCD swizzle: flat -> (bx, by, n); 540 = 12*45 blocks per batch
    int flat = blockIdx.x;
    int swz  = (flat & 7) * 1080 + (flat >> 3);
    int n    = swz / 540;
    int rem  = swz - n * 540;
    int by   = rem / 12;
    int bx   = rem - by * 12;

    int wv = threadIdx.x >> 6;
    int l  = threadIdx.x & 63;
    int ow0 = bx * 32;
    int oh0 = by * 8 + wv * 2;

    int m    = l & 31;
    int half = l >> 5;
    int choff = half << 3;

    const bf16x8* bw = (const bf16x8*)(ws + BW3_OFF);

    f32x16 acc0, acc1;
    #pragma unroll
    for (int i = 0; i < 16; i++) { acc0[i] = 0.f; acc1[i] = 0.f; }

    // clamped row/col indices (same clamping as verified version)
    int row0 = oh0;     if (row0 > H2 - 1) row0 = H2 - 1;
    int row1 = oh0 + 1; if (row1 > H2 - 1) row1 = H2 - 1;
    int row2 = oh0 + 2; if (row2 > H2 - 1) row2 = H2 - 1;
    int row3 = oh0 + 3; if (row3 > H2 - 1) row3 = H2 - 1;
    int iwc[3];
    #pragma unroll
    for (int kw = 0; kw < 3; kw++) {
        int iw = ow0 + m + kw; if (iw > H2 - 1) iw = H2 - 1;
        iwc[kw] = iw;
    }

#define LD_ROW(dst, r)                                                          \
    {                                                                           \
        const size_t rb = (((size_t)n * H2 + (r)) * H2);                        \
        dst[0] = *(const bf16x8*)(c2h + ((rb + iwc[0]) << 4) + choff);          \
        dst[1] = *(const bf16x8*)(c2h + ((rb + iwc[1]) << 4) + choff);          \
        dst[2] = *(const bf16x8*)(c2h + ((rb + iwc[2]) << 4) + choff);          \
    }

    bf16x8 ar0[3], ar1[3], ar2[3], ar3[3];
    LD_ROW(ar0, row0);
    LD_ROW(ar1, row1);
    // kh = 0: acc0 uses row0, acc1 uses row1, taps 0..2
    {
        bf16x8 wt0 = bw[0 * 64 + l], wt1 = bw[1 * 64 + l], wt2 = bw[2 * 64 + l];
        acc0 = __builtin_amdgcn_mfma_f32_32x32x16_bf16(ar0[0], wt0, acc0, 0, 0, 0);
        acc1 = __builtin_amdgcn_mfma_f32_32x32x16_bf16(ar1[0], wt0, acc1, 0, 0, 0);
        acc0 = __builtin_amdgcn_mfma_f32_32x32x16_bf16(ar0[1], wt1, acc0, 0, 0, 0);
        acc1 = __builtin_amdgcn_mfma_f32_32x32x16_bf16(ar1[1], wt1, acc1, 0, 0, 0);
        acc0 = __builtin_amdgcn_mfma_f32_32x32x16_bf16(ar0[2], wt2, acc0, 0, 0, 0);
        acc1 = __builtin_amdgcn_mfma_f32_32x32x16_bf16(ar1[2], wt2, acc1, 0, 0, 0);
    }
    LD_ROW(ar2, row2);
    // kh = 1: acc0 uses row1, acc1 uses row2, taps 3..5
    {
        bf16x8 wt0 = bw[3 * 64 + l], wt1 = bw[4 * 64 + l], wt2 = bw[5 * 64 + l];
        acc0 = __builtin_amdgcn_mfma_f32_32x32x16_bf16(ar1[0], wt0, acc0, 0, 0, 0);
        acc1 = __builtin_amdgcn_mfma_f32_32x32x16_bf16(ar2[0], wt0, acc1, 0, 0, 0);
        acc0 = __builtin_amdgcn_mfma_f32_32x32x16_bf16(ar1[1], wt1, acc0, 0, 0, 0);
        acc1 = __builtin_amdgcn_mfma_f32_32x32x16_bf16(ar2[1], wt1, acc1, 0, 0, 0);
        acc0 = __builtin_amdgcn_mfma_f32_32x32x16_bf16(ar1[2], wt2, acc0, 0, 0, 0);
        acc1 = __builtin_amdgcn_mfma_f32_32x32x16_bf16(ar2[2], wt2, acc1, 0, 0, 0);
    }
    LD_ROW(ar3, row3);
    // kh = 2: acc0 uses row2, acc1 uses row3, taps 6..8
    {
        bf16x8 wt0 = bw[6 * 64 + l], wt1 = bw[7 * 64 + l], wt2 = bw[8 * 64 + l];
        acc0 = __builtin_amdgcn_mfma_f32_32x32x16_bf16(ar2[0], wt0, acc0, 0, 0, 0);
        acc1 = __builtin_amdgcn_mfma_f32_32x32x16_bf16(ar3[0], wt0, acc1, 0, 0, 0);
        acc0 = __builtin_amdgcn_mfma_f32_32x32x16_bf16(ar2[1], wt1, acc0, 0, 0, 0);
        acc1 = __builtin_amdgcn_mfma_f32_32x32x16_bf16(ar3[1], wt1, acc1, 0, 0, 0);
        acc0 = __builtin_amdgcn_mfma_f32_32x32x16_bf16(ar2[2], wt2, acc0, 0, 0, 0);
        acc1 = __builtin_amdgcn_mfma_f32_32x32x16_bf16(ar3[2], wt2, acc1, 0, 0, 0);
    }
#undef LD_ROW

    __shared__ float hbuf[4][64 * 33];
    float* hb = hbuf[wv];
    float bb = b3[m], aa = a3[m];
    #pragma unroll
    for (int t = 0; t < 2; t++) {
        #pragma unroll
        for (int r = 0; r < 16; r++) {
            int mprime = (r & 3) + ((r >> 2) << 3) + (half << 2);
            float v = (t ? acc1[r] : acc0[r]) + bb;
            v = v >= 0.f ? v : aa * v;
            hb[(t * 32 + mprime) * 33 + m] = v;
        }
    }
    __syncthreads();

    int poh = oh0 + (l >> 5);
    int pow_ = ow0 + (l & 31);
    float h[32];
    #pragma unroll
    for (int c = 0; c < 32; c++) h[c] = hb[l * 33 + c];

    float l0 = b41[0], l1 = b41[1];
    float r0 = b42[0], r1 = b42[1], r2 = b42[2], r3 = b42[3];
    #pragma unroll
    for (int c = 0; c < 32; c++) {
        float hv = h[c];
        l0 = fmaf(hv, w41[c],      l0);
        l1 = fmaf(hv, w41[32 + c], l1);
        r0 = fmaf(hv, w42[c],      r0);
        r1 = fmaf(hv, w42[32 + c], r1);
        r2 = fmaf(hv, w42[64 + c], r2);
        r3 = fmaf(hv, w42[96 + c], r3);
    }
    float mx  = fmaxf(l0, l1);
    float e0 = __expf(l0 - mx), e1 = __expf(l1 - mx);
    float inv = 1.0f / (e0 + e1);

    if (poh < H3 && pow_ < H3) {
        const size_t sp = (size_t)H3 * H3;
        size_t pos = (size_t)poh * H3 + pow_;
        float* reg  = out;
        float* prob = out + (size_t)16 * 4 * sp;
        reg[((size_t)(n * 4 + 0)) * sp + pos] = r0;
        reg[((size_t)(n * 4 + 1)) * sp + pos] = r1;
        reg[((size_t)(n * 4 + 2)) * sp + pos] = r2;
        reg[((size_t)(n * 4 + 3)) * sp + pos] = r3;
        prob[((size_t)(n * 2 + 0)) * sp + pos] = e0 * inv;
        prob[((size_t)(n * 2 + 1)) * sp + pos] = e1 * inv;
    }
}

extern "C" void kernel_launch(void* const* d_in, const int* in_sizes, int n_in,
                              void* d_out, int out_size, void* d_ws, size_t ws_size,
                              hipStream_t stream) {
    const float* x   = (const float*)d_in[0];
    const float* w1  = (const float*)d_in[1];
    const float* b1  = (const float*)d_in[2];
    const float* a1  = (const float*)d_in[3];
    const float* w2  = (const float*)d_in[4];
    const float* b2  = (const float*)d_in[5];
    const float* a2  = (const float*)d_in[6];
    const float* w3  = (const float*)d_in[7];
    const float* b3  = (const float*)d_in[8];
    const float* a3  = (const float*)d_in[9];
    const float* w41 = (const float*)d_in[10];
    const float* b41 = (const float*)d_in[11];
    const float* w42 = (const float*)d_in[12];
    const float* b42 = (const float*)d_in[13];
    float* out = (float*)d_out;
    float* ws  = (float*)d_ws;

    __hip_bfloat16* p16 = (__hip_bfloat16*)(ws + P16_OFF);
    __hip_bfloat16* c2h = (__hip_bfloat16*)(ws + C2H_OFF);

    repack_kernel<<<29, 256, 0, stream>>>(w1, b1, w2, w3, ws);

    {
        dim3 grid((PH + 127) / 128, PH, 16);
        conv1_pool_kernel<<<grid, 128, 0, stream>>>(x, ws, a1, p16);
    }
    {
        conv2_mfma_kernel<<<8640, 256, 0, stream>>>(p16, ws, b2, a2, c2h);
    }
    {
        conv3_heads_kernel<<<8640, 256, 0, stream>>>(c2h, ws, b3, a3,
                                                     w41, b41, w42, b42, out);
    }
}

// Round 11
// 281.500 us; speedup vs baseline: 1.2216x; 1.0438x over previous
//
#include <hip/hip_runtime.h>
#include <hip/hip_bf16.h>
#include <cstddef>

// ---------------------------------------------------------------------------
// MTCNN P-Net forward, NCHW in/out.
//   x[16,3,720,720] -> norm -> conv1(3->10,3x3)+PReLU -> maxpool2 (fp32 math)
//     -> pooled NHWC bf16 (padded 10->16 ch)
//     -> conv2(16->16,3x3) via MFMA 16x16x32 bf16 -> NHWC bf16
//     -> conv3(16->32,3x3)+PReLU via MFMA 32x32x16 bf16, fused heads
//   out = concat(reg[16,4,355,355], prob[16,2,355,355]) flat fp32
// ---------------------------------------------------------------------------

#define H1 718
#define PH 359   // pooled spatial
#define H2 357   // conv2 out spatial
#define H3 355   // conv3 out spatial

// workspace layout (float offsets)
#define W1R_OFF 0              // 270 fp32, pre-scaled by 1/128
#define B1R_OFF 288            // 10 fp32 (norm folded in)
#define AW2_OFF 320            // 2560 bf16 = 1280 fl: conv2 A-frags [step][lane][8]
#define BW3_OFF 1600           // 4608 bf16 = 2304 fl: conv3 B-frags [tap][lane][8]
#define P16_OFF 4096           // pooled NHWC bf16 [16,359,359,16] = 16496768 fl
#define C2H_OFF 16500864       // conv2 out NHWC bf16 [16,357,357,16] = 16313472 fl

typedef short bf16x8 __attribute__((ext_vector_type(8)));
typedef float f32x2  __attribute__((ext_vector_type(2)));
typedef float f32x4  __attribute__((ext_vector_type(4)));
typedef float f32x16 __attribute__((ext_vector_type(16)));
typedef unsigned short ushort4v __attribute__((ext_vector_type(4)));

// ---------------------------------------------------------------------------
// Weight repack — parallelized across 29 blocks (R6; verified).
// ---------------------------------------------------------------------------
__global__ void repack_kernel(const float* __restrict__ w1, const float* __restrict__ b1,
                              const float* __restrict__ w2, const float* __restrict__ w3,
                              float* __restrict__ ws) {
    int t = threadIdx.x;
    int bid = blockIdx.x;
    if (bid == 0) {
        const float S = 0.0078125f;
        for (int i = t; i < 270; i += 256) ws[W1R_OFF + i] = w1[i] * S;
        if (t < 10) {
            float s = 0.f;
            for (int i = 0; i < 27; i++) s += w1[t * 27 + i];
            ws[B1R_OFF + t] = b1[t] - 127.5f * S * s;
        }
    } else if (bid <= 10) {
        int e = (bid - 1) * 256 + t;  // 0..2559
        unsigned short* aw2 = (unsigned short*)(ws + AW2_OFF);
        int s = e >> 9;              // K-step 0..4
        int rem = e & 511;
        int l = rem >> 3, j = rem & 7;
        int q = l >> 4, co = l & 15;
        int tap = 2 * s + (q >> 1);
        int ci  = ((q & 1) << 3) + j;
        float v = (tap < 9 && ci < 10) ? w2[co * 90 + ci * 9 + tap] : 0.f;
        __hip_bfloat16 h = __float2bfloat16(v);
        aw2[e] = *(unsigned short*)&h;
    } else {
        int e = (bid - 11) * 256 + t; // 0..4607
        unsigned short* bw3 = (unsigned short*)(ws + BW3_OFF);
        int tap = e >> 9;
        int rem = e & 511;
        int l = rem >> 3, j = rem & 7;
        int kh = tap / 3, kw = tap % 3;
        int co = l & 31, ci = ((l >> 5) << 3) + j;
        float v = w3[co * 144 + ci * 9 + kh * 3 + kw];
        __hip_bfloat16 h = __float2bfloat16(v);
        bw3[e] = *(unsigned short*)&h;
    }
}

// ---------------------------------------------------------------------------
// Stage 1: norm+conv1+PReLU+maxpool fused, all 10 channels per thread.
// R11: packed-fp32 variant of the R0 body. MI355X's 157.3 TF fp32 peak is
// 2 FLOP/lane/cy, i.e. it assumes v_pk_fma_f32 (VOP3P); scalar v_fma_f32
// issues at half that. conv1 is issue-bound (VALUBusy 62%), so pairing the
// (px0,px1) and (px2,px3) accumulators into f32x2 halves the FMA issue count
// (1080 -> 540 packed).
//  - acc01/acc23[c]: f32x2 pairs (same accumulation ORDER -> bit-identical)
//  - 12 window pairs per ci built straight from the float2 loads
//    ((v0.x,v0.y),(v0.y,v1.x),(v1.x,v1.y) per row); win never materialized
//  - __builtin_elementwise_fma guarantees fma semantics == R0's fmaf
//  - peak live ~74 (40 acc + 24 pr + addr) — under the proven spill ceiling
//  - weights stay wave-uniform (SGPR operands)
// Fallback risk: if the backend declines v_pk_fma_f32 it emits 2 scalar fmas
// -> exactly the R0 schedule, neutral.
// grid: (3, 359, 16), block 128.
// ---------------------------------------------------------------------------
__global__ void conv1_pool_kernel(const float* __restrict__ x,
                                  const float* __restrict__ ws,
                                  const float* __restrict__ a1,
                                  __hip_bfloat16* __restrict__ p16) {
    int pw = blockIdx.x * blockDim.x + threadIdx.x;
    int ph = blockIdx.y;
    int n  = blockIdx.z;
    if (pw >= PH) return;
    int iy = 2 * ph, ix = 2 * pw;

    f32x2 acc01[10], acc23[10];
    #pragma unroll
    for (int c = 0; c < 10; c++) {
        acc01[c] = (f32x2){0.f, 0.f};
        acc23[c] = (f32x2){0.f, 0.f};
    }

    #pragma unroll
    for (int ci = 0; ci < 3; ci++) {
        const float* xp = x + (((size_t)(n * 3 + ci) * 720 + iy) * 720 + ix);
        // window pairs: pr[r][kw] = (win[r][kw], win[r][kw+1])
        f32x2 pr[4][3];
        #pragma unroll
        for (int r = 0; r < 4; r++) {
            float2 v0 = *(const float2*)(xp + r * 720);
            float2 v1 = *(const float2*)(xp + r * 720 + 2);
            pr[r][0] = (f32x2){v0.x, v0.y};
            pr[r][1] = (f32x2){v0.y, v1.x};
            pr[r][2] = (f32x2){v1.x, v1.y};
        }
        #pragma unroll
        for (int c = 0; c < 10; c++) {
            const float* wk = ws + W1R_OFF + c * 27 + ci * 9;
            #pragma unroll
            for (int kh = 0; kh < 3; kh++)
                #pragma unroll
                for (int kw = 0; kw < 3; kw++) {
                    float wv = wk[kh * 3 + kw];
                    f32x2 wv2 = (f32x2){wv, wv};
                    acc01[c] = __builtin_elementwise_fma(pr[kh    ][kw], wv2, acc01[c]);
                    acc23[c] = __builtin_elementwise_fma(pr[kh + 1][kw], wv2, acc23[c]);
                }
        }
    }

    __hip_bfloat16 o[16];
    #pragma unroll
    for (int c = 0; c < 10; c++) {
        float b = ws[B1R_OFF + c], al = a1[c];
        float s0 = acc01[c][0] + b, s1 = acc01[c][1] + b;
        float s2 = acc23[c][0] + b, s3 = acc23[c][1] + b;
        s0 = s0 >= 0.f ? s0 : al * s0;
        s1 = s1 >= 0.f ? s1 : al * s1;
        s2 = s2 >= 0.f ? s2 : al * s2;
        s3 = s3 >= 0.f ? s3 : al * s3;
        o[c] = __float2bfloat16(fmaxf(fmaxf(s0, s1), fmaxf(s2, s3)));
    }
    #pragma unroll
    for (int c = 10; c < 16; c++) o[c] = __float2bfloat16(0.f);

    float4* dst = (float4*)(p16 + (((size_t)n * PH + ph) * PH + pw) * 16);
    dst[0] = ((float4*)o)[0];
    dst[1] = ((float4*)o)[1];
}

// ---------------------------------------------------------------------------
// Stage 2: conv2 3x3 (16pad->16) + bias + PReLU, MFMA 16x16x32 bf16.
// R8 diet + R9 XCD swizzle (both verified; swizzle netted −11 us with conv3).
// grid: 8640 flat, block 256. No barriers.
// ---------------------------------------------------------------------------
__global__ __launch_bounds__(256)
void conv2_mfma_kernel(const __hip_bfloat16* __restrict__ p16,
                       const float* __restrict__ ws,
                       const float* __restrict__ b2,
                       const float* __restrict__ a2,
                       __hip_bfloat16* __restrict__ c2h) {
    // XCD swizzle: flat -> (bx, by, n)
    int flat = blockIdx.x;                     // 0..8639
    int swz  = (flat & 7) * 1080 + (flat >> 3);
    int n    = swz / 540;                      // 540 = 6*90 blocks per batch
    int rem  = swz - n * 540;
    int by   = rem / 6;
    int bx   = rem - by * 6;

    int wv = threadIdx.x >> 6;
    int l  = threadIdx.x & 63;
    int oh  = by * 4 + wv;
    int ow0 = bx * 64;
    if (oh >= H2) return;

    int pxl = l & 15;          // B col: px within tile
    int q   = l >> 4;
    int taph = q >> 1;         // which tap within K-step (0: lanes<32, 1: >=32)
    int choff = (q & 1) << 3;  // channel sub-chunk

    const bf16x8* aw = (const bf16x8*)(ws + AW2_OFF);
    bf16x8 afr[5];
    #pragma unroll
    for (int s = 0; s < 5; s++) afr[s] = aw[s * 64 + l];

    f32x4 acc[4];
    #pragma unroll
    for (int t = 0; t < 4; t++)
        #pragma unroll
        for (int i = 0; i < 4; i++) acc[t][i] = 0.f;

    #pragma unroll
    for (int s = 0; s < 5; s++) {
        int tap = 2 * s + taph;           // constant-per-half; folds to cndmask
        int kh = tap / 3, kw = tap - kh * 3;
        int ih = oh + kh;                 // <= 358 for real taps; pad tap redirected
        int col = ow0 + pxl + kw;
        int off = ((n * PH + ih) * PH + col) * 16 + choff;  // bf16 elements
        const bf16x8* bp = (const bf16x8*)(p16 + off);
        if (s == 4) {
            // tap 9 (taph=1): A-frag is all-zero; just need finite B.
            bp = taph ? (const bf16x8*)(p16 + choff) : bp;
        }
        acc[0] = __builtin_amdgcn_mfma_f32_16x16x32_bf16(afr[s], bp[0],  acc[0], 0, 0, 0);
        acc[1] = __builtin_amdgcn_mfma_f32_16x16x32_bf16(afr[s], bp[32], acc[1], 0, 0, 0);
        acc[2] = __builtin_amdgcn_mfma_f32_16x16x32_bf16(afr[s], bp[64], acc[2], 0, 0, 0);
        acc[3] = __builtin_amdgcn_mfma_f32_16x16x32_bf16(afr[s], bp[96], acc[3], 0, 0, 0);
    }

    // epilogue: bias+PReLU; lane's elements are (c_out = q*4+r, px = pxl)
    float bb[4], aa[4];
    #pragma unroll
    for (int r = 0; r < 4; r++) { bb[r] = b2[q * 4 + r]; aa[r] = a2[q * 4 + r]; }

    #pragma unroll
    for (int t = 0; t < 4; t++) {
        int px = ow0 + t * 16 + pxl;
        if (px < H2) {
            ushort4v pk;
            #pragma unroll
            for (int r = 0; r < 4; r++) {
                float v = acc[t][r] + bb[r];
                v = v >= 0.f ? v : aa[r] * v;
                __hip_bfloat16 h = __float2bfloat16(v);
                pk[r] = *(unsigned short*)&h;
            }
            *(ushort4v*)(c2h + (((size_t)n * H2 + oh) * H2 + px) * 16 + q * 4) = pk;
        }
    }
}

// ---------------------------------------------------------------------------
// Stage 3: conv3 3x3 (16->32) + PReLU + heads, MFMA 32x32x16 bf16.
// R10 (verified, kept): __launch_bounds__(256,4), per-kh B-frag loads,
// R6b row-dedup, R9 XCD swizzle. grid: 8640 flat, block 256.
// ---------------------------------------------------------------------------
__global__ __launch_bounds__(256, 4)
void conv3_heads_kernel(const __hip_bfloat16* __restrict__ c2h,
                        const float* __restrict__ ws,
                        const float* __restrict__ b3,
                        const float* __restrict__ a3,
                        const float* __restrict__ w41,
                        const float* __restrict__ b41,
                        const float* __restrict__ w42,
                        const float* __restrict__ b42,
                        float* __restrict__ out) {
    // XCD swizzle: flat -> (bx, by, n); 540 = 12*45 blocks per batch
    int flat = blockIdx.x;
    int swz  = (flat & 7) * 1080 + (flat >> 3);
    int n    = swz / 540;
    int rem  = swz - n * 540;
    int by   = rem / 12;
    int bx   = rem - by * 12;

    int wv = threadIdx.x >> 6;
    int l  = threadIdx.x & 63;
    int ow0 = bx * 32;
    int oh0 = by * 8 + wv * 2;

    int m    = l & 31;
    int half = l >> 5;
    int choff = half << 3;

    const bf16x8* bw = (const bf16x8*)(ws + BW3_OFF);

    f32x16 acc0, acc1;
    #pragma unroll
    for (int i = 0; i < 16; i++) { acc0[i] = 0.f; acc1[i] = 0.f; }

    // clamped row/col indices (same clamping as verified version)
    int row0 = oh0;     if (row0 > H2 - 1) row0 = H2 - 1;
    int row1 = oh0 + 1; if (row1 > H2 - 1) row1 = H2 - 1;
    int row2 = oh0 + 2; if (row2 > H2 - 1) row2 = H2 - 1;
    int row3 = oh0 + 3; if (row3 > H2 - 1) row3 = H2 - 1;
    int iwc[3];
    #pragma unroll
    for (int kw = 0; kw < 3; kw++) {
        int iw = ow0 + m + kw; if (iw > H2 - 1) iw = H2 - 1;
        iwc[kw] = iw;
    }

#define LD_ROW(dst, r)                                                          \
    {                                                                           \
        const size_t rb = (((size_t)n * H2 + (r)) * H2);                        \
        dst[0] = *(const bf16x8*)(c2h + ((rb + iwc[0]) << 4) + choff);          \
        dst[1] = *(const bf16x8*)(c2h + ((rb + iwc[1]) << 4) + choff);          \
        dst[2] = *(const bf16x8*)(c2h + ((rb + iwc[2]) << 4) + choff);          \
    }

    bf16x8 ar0[3], ar1[3], ar2[3], ar3[3];
    LD_ROW(ar0, row0);
    LD_ROW(ar1, row1);
    // kh = 0: acc0 uses row0, acc1 uses row1, taps 0..2
    {
        bf16x8 wt0 = bw[0 * 64 + l], wt1 = bw[1 * 64 + l], wt2 = bw[2 * 64 + l];
        acc0 = __builtin_amdgcn_mfma_f32_32x32x16_bf16(ar0[0], wt0, acc0, 0, 0, 0);
        acc1 = __builtin_amdgcn_mfma_f32_32x32x16_bf16(ar1[0], wt0, acc1, 0, 0, 0);
        acc0 = __builtin_amdgcn_mfma_f32_32x32x16_bf16(ar0[1], wt1, acc0, 0, 0, 0);
        acc1 = __builtin_amdgcn_mfma_f32_32x32x16_bf16(ar1[1], wt1, acc1, 0, 0, 0);
        acc0 = __builtin_amdgcn_mfma_f32_32x32x16_bf16(ar0[2], wt2, acc0, 0, 0, 0);
        acc1 = __builtin_amdgcn_mfma_f32_32x32x16_bf16(ar1[2], wt2, acc1, 0, 0, 0);
    }
    LD_ROW(ar2, row2);
    // kh = 1: acc0 uses row1, acc1 uses row2, taps 3..5
    {
        bf16x8 wt0 = bw[3 * 64 + l], wt1 = bw[4 * 64 + l], wt2 = bw[5 * 64 + l];
        acc0 = __builtin_amdgcn_mfma_f32_32x32x16_bf16(ar1[0], wt0, acc0, 0, 0, 0);
        acc1 = __builtin_amdgcn_mfma_f32_32x32x16_bf16(ar2[0], wt0, acc1, 0, 0, 0);
        acc0 = __builtin_amdgcn_mfma_f32_32x32x16_bf16(ar1[1], wt1, acc0, 0, 0, 0);
        acc1 = __builtin_amdgcn_mfma_f32_32x32x16_bf16(ar2[1], wt1, acc1, 0, 0, 0);
        acc0 = __builtin_amdgcn_mfma_f32_32x32x16_bf16(ar1[2], wt2, acc0, 0, 0, 0);
        acc1 = __builtin_amdgcn_mfma_f32_32x32x16_bf16(ar2[2], wt2, acc1, 0, 0, 0);
    }
    LD_ROW(ar3, row3);
    // kh = 2: acc0 uses row2, acc1 uses row3, taps 6..8
    {
        bf16x8 wt0 = bw[6 * 64 + l], wt1 = bw[7 * 64 + l], wt2 = bw[8 * 64 + l];
        acc0 = __builtin_amdgcn_mfma_f32_32x32x16_bf16(ar2[0], wt0, acc0, 0, 0, 0);
        acc1 = __builtin_amdgcn_mfma_f32_32x32x16_bf16(ar3[0], wt0, acc1, 0, 0, 0);
        acc0 = __builtin_amdgcn_mfma_f32_32x32x16_bf16(ar2[1], wt1, acc0, 0, 0, 0);
        acc1 = __builtin_amdgcn_mfma_f32_32x32x16_bf16(ar3[1], wt1, acc1, 0, 0, 0);
        acc0 = __builtin_amdgcn_mfma_f32_32x32x16_bf16(ar2[2], wt2, acc0, 0, 0, 0);
        acc1 = __builtin_amdgcn_mfma_f32_32x32x16_bf16(ar3[2], wt2, acc1, 0, 0, 0);
    }
#undef LD_ROW

    __shared__ float hbuf[4][64 * 33];
    float* hb = hbuf[wv];
    float bb = b3[m], aa = a3[m];
    #pragma unroll
    for (int t = 0; t < 2; t++) {
        #pragma unroll
        for (int r = 0; r < 16; r++) {
            int mprime = (r & 3) + ((r >> 2) << 3) + (half << 2);
            float v = (t ? acc1[r] : acc0[r]) + bb;
            v = v >= 0.f ? v : aa * v;
            hb[(t * 32 + mprime) * 33 + m] = v;
        }
    }
    __syncthreads();

    int poh = oh0 + (l >> 5);
    int pow_ = ow0 + (l & 31);
    float h[32];
    #pragma unroll
    for (int c = 0; c < 32; c++) h[c] = hb[l * 33 + c];

    float l0 = b41[0], l1 = b41[1];
    float r0 = b42[0], r1 = b42[1], r2 = b42[2], r3 = b42[3];
    #pragma unroll
    for (int c = 0; c < 32; c++) {
        float hv = h[c];
        l0 = fmaf(hv, w41[c],      l0);
        l1 = fmaf(hv, w41[32 + c], l1);
        r0 = fmaf(hv, w42[c],      r0);
        r1 = fmaf(hv, w42[32 + c], r1);
        r2 = fmaf(hv, w42[64 + c], r2);
        r3 = fmaf(hv, w42[96 + c], r3);
    }
    float mx  = fmaxf(l0, l1);
    float e0 = __expf(l0 - mx), e1 = __expf(l1 - mx);
    float inv = 1.0f / (e0 + e1);

    if (poh < H3 && pow_ < H3) {
        const size_t sp = (size_t)H3 * H3;
        size_t pos = (size_t)poh * H3 + pow_;
        float* reg  = out;
        float* prob = out + (size_t)16 * 4 * sp;
        reg[((size_t)(n * 4 + 0)) * sp + pos] = r0;
        reg[((size_t)(n * 4 + 1)) * sp + pos] = r1;
        reg[((size_t)(n * 4 + 2)) * sp + pos] = r2;
        reg[((size_t)(n * 4 + 3)) * sp + pos] = r3;
        prob[((size_t)(n * 2 + 0)) * sp + pos] = e0 * inv;
        prob[((size_t)(n * 2 + 1)) * sp + pos] = e1 * inv;
    }
}

extern "C" void kernel_launch(void* const* d_in, const int* in_sizes, int n_in,
                              void* d_out, int out_size, void* d_ws, size_t ws_size,
                              hipStream_t stream) {
    const float* x   = (const float*)d_in[0];
    const float* w1  = (const float*)d_in[1];
    const float* b1  = (const float*)d_in[2];
    const float* a1  = (const float*)d_in[3];
    const float* w2  = (const float*)d_in[4];
    const float* b2  = (const float*)d_in[5];
    const float* a2  = (const float*)d_in[6];
    const float* w3  = (const float*)d_in[7];
    const float* b3  = (const float*)d_in[8];
    const float* a3  = (const float*)d_in[9];
    const float* w41 = (const float*)d_in[10];
    const float* b41 = (const float*)d_in[11];
    const float* w42 = (const float*)d_in[12];
    const float* b42 = (const float*)d_in[13];
    float* out = (float*)d_out;
    float* ws  = (float*)d_ws;

    __hip_bfloat16* p16 = (__hip_bfloat16*)(ws + P16_OFF);
    __hip_bfloat16* c2h = (__hip_bfloat16*)(ws + C2H_OFF);

    repack_kernel<<<29, 256, 0, stream>>>(w1, b1, w2, w3, ws);

    {
        dim3 grid((PH + 127) / 128, PH, 16);
        conv1_pool_kernel<<<grid, 128, 0, stream>>>(x, ws, a1, p16);
    }
    {
        conv2_mfma_kernel<<<8640, 256, 0, stream>>>(p16, ws, b2, a2, c2h);
    }
    {
        conv3_heads_kernel<<<8640, 256, 0, stream>>>(c2h, ws, b3, a3,
                                                     w41, b41, w42, b42, out);
    }
}